// Round 1
// baseline (3918.571 us; speedup 1.0000x reference)
//
#include <hip/hip_runtime.h>

// Problem constants
#define BB 8
#define NB 32768
#define RR 32
#define VV (32*32*32)
#define INV_SQRT2 0.70710678118654752440f

static __device__ __forceinline__ float lrelu(float x) { return x > 0.f ? x : 0.01f * x; }
static __device__ __forceinline__ float rl(float v, int i) {
    return __uint_as_float((unsigned)__builtin_amdgcn_readlane(__float_as_uint(v), i));
}

static __device__ __forceinline__ void corner_setup(float px, float py, float pz,
    int& c0x, int& c0y, int& c0z, int& c1x, int& c1y, int& c1z,
    float& fx, float& fy, float& fz)
{
    float cx = fminf(fmaxf(px, 0.f), 1.f) * 31.f;
    float cy = fminf(fmaxf(py, 0.f), 1.f) * 31.f;
    float cz = fminf(fmaxf(pz, 0.f), 1.f) * 31.f;
    float f0x = floorf(cx), f0y = floorf(cy), f0z = floorf(cz);
    c0x = (int)f0x; c0y = (int)f0y; c0z = (int)f0z;
    fx = cx - f0x; fy = cy - f0y; fz = cz - f0z;
    c1x = min(c0x + 1, 31); c1y = min(c0y + 1, 31); c1z = min(c0z + 1, 31);
}

// Reorder conv weights [O][I][27] -> [t][i][o] for coalesced per-tap staging.
__global__ __launch_bounds__(256) void k_reorder_w(const float* __restrict__ w1,
                                                   const float* __restrict__ w2,
                                                   float* __restrict__ wr1,
                                                   float* __restrict__ wr2)
{
    int idx = blockIdx.x * 256 + threadIdx.x;
    if (idx >= 27 * 64 * 64) return;
    int t = idx >> 12;          // /4096
    int r = idx & 4095;
    int i = r >> 6, o = r & 63;
    wr1[idx] = w1[(o * 64 + i) * 27 + t];
    wr2[idx] = w2[(o * 64 + i) * 27 + t];
}

// Trilinear scatter (atomics) + point-branch GN1 stats (sum, sumsq per channel).
__global__ __launch_bounds__(256) void k_voxelize(const float* __restrict__ pts,
                                                  const float* __restrict__ feat,
                                                  float* __restrict__ fsum,
                                                  float* __restrict__ wsum,
                                                  float* __restrict__ statsP)
{
    __shared__ float sred[256];
    const int b = blockIdx.x >> 9;
    const int n0 = (blockIdx.x & 511) * 64;
    const int wid = threadIdx.x >> 6, lane = threadIdx.x & 63;
    float s = 0.f, s2 = 0.f;
    for (int j = 0; j < 16; ++j) {
        const int base = b * NB + n0 + wid * 16 + j;
        const float f = feat[base * 64 + lane];
        s += f; s2 += f * f;
        const float px = pts[base * 3 + 0], py = pts[base * 3 + 1], pz = pts[base * 3 + 2];
        int c0x, c0y, c0z, c1x, c1y, c1z; float fx, fy, fz;
        corner_setup(px, py, pz, c0x, c0y, c0z, c1x, c1y, c1z, fx, fy, fz);
        const float w0x = 1.f - fx, w0y = 1.f - fy, w0z = 1.f - fz;
#pragma unroll
        for (int k = 0; k < 8; ++k) {
            const int cx = (k & 4) ? c1x : c0x;
            const int cy = (k & 2) ? c1y : c0y;
            const int cz = (k & 1) ? c1z : c0z;
            const float w = ((k & 4) ? fx : w0x) * ((k & 2) ? fy : w0y) * ((k & 1) ? fz : w0z);
            atomicAdd(&fsum[(b * VV + (cx * RR + cy) * RR + cz) * 64 + lane], w * f);
        }
        if (lane < 8) {
            const int cx = (lane & 4) ? c1x : c0x;
            const int cy = (lane & 2) ? c1y : c0y;
            const int cz = (lane & 1) ? c1z : c0z;
            const float w = ((lane & 4) ? fx : w0x) * ((lane & 2) ? fy : w0y) * ((lane & 1) ? fz : w0z);
            atomicAdd(&wsum[b * VV + (cx * RR + cy) * RR + cz], w);
        }
    }
    sred[threadIdx.x] = s; __syncthreads();
    if (threadIdx.x < 64) {
        float t = sred[threadIdx.x] + sred[threadIdx.x + 64] + sred[threadIdx.x + 128] + sred[threadIdx.x + 192];
        atomicAdd(&statsP[(b * 64 + threadIdx.x) * 2], t);
    }
    __syncthreads();
    sred[threadIdx.x] = s2; __syncthreads();
    if (threadIdx.x < 64) {
        float t = sred[threadIdx.x] + sred[threadIdx.x + 64] + sred[threadIdx.x + 128] + sred[threadIdx.x + 192];
        atomicAdd(&statsP[(b * 64 + threadIdx.x) * 2 + 1], t);
    }
}

// grid = fsum / max(wsum,1e-8) in place, + voxel GN1 stats.
__global__ __launch_bounds__(256) void k_finalize(float* __restrict__ g,
                                                  const float* __restrict__ wsum,
                                                  float* __restrict__ statsV)
{
    __shared__ float sred[256];
    const int b = blockIdx.x >> 6;
    const int v0 = (blockIdx.x & 63) * 512;
    const int wid = threadIdx.x >> 6, lane = threadIdx.x & 63;
    float s = 0.f, s2 = 0.f;
    for (int k = 0; k < 128; ++k) {
        const int vox = v0 + k * 4 + wid;
        const float w = wsum[b * VV + vox];
        const int idx = (b * VV + vox) * 64 + lane;
        const float val = g[idx] / fmaxf(w, 1e-8f);
        g[idx] = val;
        s += val; s2 += val * val;
    }
    sred[threadIdx.x] = s; __syncthreads();
    if (threadIdx.x < 64) {
        float t = sred[threadIdx.x] + sred[threadIdx.x + 64] + sred[threadIdx.x + 128] + sred[threadIdx.x + 192];
        atomicAdd(&statsV[(b * 64 + threadIdx.x) * 2], t);
    }
    __syncthreads();
    sred[threadIdx.x] = s2; __syncthreads();
    if (threadIdx.x < 64) {
        float t = sred[threadIdx.x] + sred[threadIdx.x + 64] + sred[threadIdx.x + 128] + sred[threadIdx.x + 192];
        atomicAdd(&statsV[(b * 64 + threadIdx.x) * 2 + 1], t);
    }
}

// stats -> per-channel affine (a,b): y = a*x + b implements groupnorm (groups of 2 ch x 32768).
__global__ void k_coef(const float* __restrict__ stats, const float* __restrict__ gamma,
                       const float* __restrict__ beta, float* __restrict__ coef)
{
    int tid = threadIdx.x;           // 512 threads: b=tid>>6, c=tid&63
    int b = tid >> 6, c = tid & 63, g = c >> 1;
    float s = stats[(b * 64 + 2 * g) * 2] + stats[(b * 64 + 2 * g + 1) * 2];
    float q = stats[(b * 64 + 2 * g) * 2 + 1] + stats[(b * 64 + 2 * g + 1) * 2 + 1];
    float mean = s / 65536.f;
    float var = q / 65536.f - mean * mean;
    float a = gamma[c] * rsqrtf(var + 1e-5f);
    coef[(b * 64 + c) * 2] = a;
    coef[(b * 64 + c) * 2 + 1] = beta[c] - mean * a;
}

// 3x3x3 conv, C=64->64, SAME. Input staged to LDS with fused per-channel affine+lrelu.
// Tile: 4x4x8 = 128 voxels; thread = 4 voxels (z) x 8 out-channels.
// Optional: stats accumulation (conv1) or residual+scale epilogue writing in place (conv2).
__global__ __launch_bounds__(256) void k_conv(const float* __restrict__ in,
                                              const float* __restrict__ wr,
                                              const float* __restrict__ bias,
                                              const float* __restrict__ coef_in,
                                              float* out,
                                              float* __restrict__ statsOut,
                                              const float* resid,
                                              const float* __restrict__ coef_res)
{
    __shared__ float in_lds[64 * 361];   // [ch][halo voxel 6x6x10], stride 361 (odd -> no bank conflict)
    __shared__ float w_lds[64 * 64];     // [i][o] for current tap
    const int b = blockIdx.x >> 8;
    const int tile = blockIdx.x & 255;
    const int gx0 = (tile >> 5) * 4, gy0 = ((tile >> 2) & 7) * 4, gz0 = (tile & 3) * 8;
    const int tid = threadIdx.x;
    const int lane = tid & 63, wid = tid >> 6;

    {   // stage halo: act = lrelu(a*x+b), zeros outside grid
        const float ai = coef_in[(b * 64 + lane) * 2];
        const float bi = coef_in[(b * 64 + lane) * 2 + 1];
        for (int hv = wid; hv < 360; hv += 4) {
            int hx = hv / 60, rem = hv - hx * 60;
            int hy = rem / 10, hz = rem - hy * 10;
            int gx = gx0 + hx - 1, gy = gy0 + hy - 1, gz = gz0 + hz - 1;
            float v = 0.f;
            if ((unsigned)gx < 32u && (unsigned)gy < 32u && (unsigned)gz < 32u)
                v = lrelu(ai * in[(b * VV + (gx * RR + gy) * RR + gz) * 64 + lane] + bi);
            in_lds[lane * 361 + hv] = v;
        }
    }

    const int cq = tid >> 5, vq = tid & 31;
    const int ox = vq >> 3, oy = (vq >> 1) & 3, zg = vq & 1;
    const int ch = cq * 8;

    float acc[4][8];
#pragma unroll
    for (int j = 0; j < 8; ++j) {
        float bj = bias[ch + j];
        acc[0][j] = bj; acc[1][j] = bj; acc[2][j] = bj; acc[3][j] = bj;
    }

    for (int t = 0; t < 27; ++t) {
        __syncthreads();
#pragma unroll
        for (int k = 0; k < 16; ++k) w_lds[k * 256 + tid] = wr[t * 4096 + k * 256 + tid];
        __syncthreads();
        const int dx = t / 9, dyz = t - dx * 9;
        const int dy = dyz / 3, dz = dyz - dy * 3;
        const int hb = ((ox + dx) * 6 + (oy + dy)) * 10 + (zg * 4 + dz);
#pragma unroll 4
        for (int i = 0; i < 64; ++i) {
            const float* ir = &in_lds[i * 361 + hb];
            const float i0 = ir[0], i1 = ir[1], i2 = ir[2], i3 = ir[3];
            const float4 wa = *(const float4*)&w_lds[i * 64 + ch];
            const float4 wb = *(const float4*)&w_lds[i * 64 + ch + 4];
            acc[0][0] += i0 * wa.x; acc[0][1] += i0 * wa.y; acc[0][2] += i0 * wa.z; acc[0][3] += i0 * wa.w;
            acc[0][4] += i0 * wb.x; acc[0][5] += i0 * wb.y; acc[0][6] += i0 * wb.z; acc[0][7] += i0 * wb.w;
            acc[1][0] += i1 * wa.x; acc[1][1] += i1 * wa.y; acc[1][2] += i1 * wa.z; acc[1][3] += i1 * wa.w;
            acc[1][4] += i1 * wb.x; acc[1][5] += i1 * wb.y; acc[1][6] += i1 * wb.z; acc[1][7] += i1 * wb.w;
            acc[2][0] += i2 * wa.x; acc[2][1] += i2 * wa.y; acc[2][2] += i2 * wa.z; acc[2][3] += i2 * wa.w;
            acc[2][4] += i2 * wb.x; acc[2][5] += i2 * wb.y; acc[2][6] += i2 * wb.z; acc[2][7] += i2 * wb.w;
            acc[3][0] += i3 * wa.x; acc[3][1] += i3 * wa.y; acc[3][2] += i3 * wa.z; acc[3][3] += i3 * wa.w;
            acc[3][4] += i3 * wb.x; acc[3][5] += i3 * wb.y; acc[3][6] += i3 * wb.z; acc[3][7] += i3 * wb.w;
        }
    }

    // epilogue
    const int gvx = gx0 + ox, gvy = gy0 + oy;
    float ar[8], br[8];
    if (resid) {
#pragma unroll
        for (int j = 0; j < 8; ++j) {
            ar[j] = coef_res[(b * 64 + ch + j) * 2];
            br[j] = coef_res[(b * 64 + ch + j) * 2 + 1];
        }
    }
    float sa[8] = {0, 0, 0, 0, 0, 0, 0, 0}, sq[8] = {0, 0, 0, 0, 0, 0, 0, 0};
#pragma unroll
    for (int v = 0; v < 4; ++v) {
        const int gvz = gz0 + zg * 4 + v;
        const int idx = (b * VV + (gvx * RR + gvy) * RR + gvz) * 64 + ch;
        if (resid) {
#pragma unroll
            for (int j = 0; j < 8; ++j)
                acc[v][j] = (acc[v][j] + ar[j] * resid[idx + j] + br[j]) * INV_SQRT2;
        }
        float4 o0 = make_float4(acc[v][0], acc[v][1], acc[v][2], acc[v][3]);
        float4 o1 = make_float4(acc[v][4], acc[v][5], acc[v][6], acc[v][7]);
        *(float4*)&out[idx] = o0;
        *(float4*)&out[idx + 4] = o1;
        if (statsOut) {
#pragma unroll
            for (int j = 0; j < 8; ++j) { sa[j] += acc[v][j]; sq[j] += acc[v][j] * acc[v][j]; }
        }
    }
    if (statsOut) {
#pragma unroll
        for (int j = 0; j < 8; ++j) {
            float a = sa[j], q = sq[j];
#pragma unroll
            for (int m = 1; m < 32; m <<= 1) { a += __shfl_xor(a, m); q += __shfl_xor(q, m); }
            if (vq == 0) {
                atomicAdd(&statsOut[(b * 64 + ch + j) * 2], a);
                atomicAdd(&statsOut[(b * 64 + ch + j) * 2 + 1], q);
            }
        }
    }
}

// Point branch conv1x1 #1: h = W @ lrelu(gn1(f)) + bias, + GN2 stats. Weights in registers,
// activation broadcast via readlane (keeps the DS pipe free).
__global__ __launch_bounds__(256) void k_point1(const float* __restrict__ feat,
                                                const float* __restrict__ W,
                                                const float* __restrict__ bias,
                                                const float* __restrict__ coefP,
                                                float* __restrict__ h1out,
                                                float* __restrict__ statsOut)
{
    __shared__ float w_lds[64 * 65];
    __shared__ float sred[256];
    const int b = blockIdx.x >> 9;
    const int n0 = (blockIdx.x & 511) * 64;
    const int wid = threadIdx.x >> 6, lane = threadIdx.x & 63;
    for (int k = threadIdx.x; k < 4096; k += 256)
        w_lds[(k & 63) * 65 + (k >> 6)] = W[k];   // w_lds[i][o] = W[o][i]
    __syncthreads();
    float wreg[64];
#pragma unroll
    for (int i = 0; i < 64; ++i) wreg[i] = w_lds[i * 65 + lane];
    const float bo = bias[lane];
    const float a = coefP[(b * 64 + lane) * 2], bb = coefP[(b * 64 + lane) * 2 + 1];
    float s = 0.f, s2 = 0.f;
    for (int j = 0; j < 16; ++j) {
        const int base = b * NB + n0 + wid * 16 + j;
        const float f = feat[base * 64 + lane];
        const float act = lrelu(a * f + bb);
        float o = bo;
#pragma unroll
        for (int i = 0; i < 64; ++i) o += rl(act, i) * wreg[i];
        h1out[base * 64 + lane] = o;
        s += o; s2 += o * o;
    }
    sred[threadIdx.x] = s; __syncthreads();
    if (threadIdx.x < 64) {
        float t = sred[threadIdx.x] + sred[threadIdx.x + 64] + sred[threadIdx.x + 128] + sred[threadIdx.x + 192];
        atomicAdd(&statsOut[(b * 64 + threadIdx.x) * 2], t);
    }
    __syncthreads();
    sred[threadIdx.x] = s2; __syncthreads();
    if (threadIdx.x < 64) {
        float t = sred[threadIdx.x] + sred[threadIdx.x + 64] + sred[threadIdx.x + 128] + sred[threadIdx.x + 192];
        atomicAdd(&statsOut[(b * 64 + threadIdx.x) * 2 + 1], t);
    }
}

// Final fused: point conv1x1 #2 + point residual + trilinear devox gather + output mix.
__global__ __launch_bounds__(256) void k_final(const float* __restrict__ pts,
                                               const float* __restrict__ feat,
                                               const float* __restrict__ h1,
                                               const float* __restrict__ W2,
                                               const float* __restrict__ bias2,
                                               const float* __restrict__ coefP1,
                                               const float* __restrict__ coefP2,
                                               const float* __restrict__ outg,
                                               float* __restrict__ out)
{
    __shared__ float w_lds[64 * 65];
    const int b = blockIdx.x >> 9;
    const int n0 = (blockIdx.x & 511) * 64;
    const int wid = threadIdx.x >> 6, lane = threadIdx.x & 63;
    for (int k = threadIdx.x; k < 4096; k += 256)
        w_lds[(k & 63) * 65 + (k >> 6)] = W2[k];
    __syncthreads();
    float wreg[64];
#pragma unroll
    for (int i = 0; i < 64; ++i) wreg[i] = w_lds[i * 65 + lane];
    const float bo = bias2[lane];
    const float a1 = coefP1[(b * 64 + lane) * 2], b1 = coefP1[(b * 64 + lane) * 2 + 1];
    const float a2 = coefP2[(b * 64 + lane) * 2], b2 = coefP2[(b * 64 + lane) * 2 + 1];
    for (int j = 0; j < 16; ++j) {
        const int base = b * NB + n0 + wid * 16 + j;
        const float f = feat[base * 64 + lane];
        const float fn = a1 * f + b1;
        const float act = lrelu(a2 * h1[base * 64 + lane] + b2);
        float o = bo;
#pragma unroll
        for (int i = 0; i < 64; ++i) o += rl(act, i) * wreg[i];
        const float ptsv = (o + fn) * INV_SQRT2;
        const float px = pts[base * 3 + 0], py = pts[base * 3 + 1], pz = pts[base * 3 + 2];
        int c0x, c0y, c0z, c1x, c1y, c1z; float fx, fy, fz;
        corner_setup(px, py, pz, c0x, c0y, c0z, c1x, c1y, c1z, fx, fy, fz);
        const float w0x = 1.f - fx, w0y = 1.f - fy, w0z = 1.f - fz;
        float dv = 0.f;
#pragma unroll
        for (int k = 0; k < 8; ++k) {
            const int cx = (k & 4) ? c1x : c0x;
            const int cy = (k & 2) ? c1y : c0y;
            const int cz = (k & 1) ? c1z : c0z;
            const float w = ((k & 4) ? fx : w0x) * ((k & 2) ? fy : w0y) * ((k & 1) ? fz : w0z);
            dv += w * outg[(b * VV + (cx * RR + cy) * RR + cz) * 64 + lane];
        }
        out[base * 64 + lane] = (ptsv + dv) * INV_SQRT2;
    }
}

extern "C" void kernel_launch(void* const* d_in, const int* in_sizes, int n_in,
                              void* d_out, int out_size, void* d_ws, size_t ws_size,
                              hipStream_t stream)
{
    const float* points   = (const float*)d_in[0];
    const float* features = (const float*)d_in[1];
    const float* conv1_w  = (const float*)d_in[2];
    const float* conv1_b  = (const float*)d_in[3];
    const float* conv2_w  = (const float*)d_in[4];
    const float* conv2_b  = (const float*)d_in[5];
    const float* g1_gamma = (const float*)d_in[6];
    const float* g1_beta  = (const float*)d_in[7];
    const float* g2_gamma = (const float*)d_in[8];
    const float* g2_beta  = (const float*)d_in[9];
    const float* p1w  = (const float*)d_in[10];
    const float* p1b  = (const float*)d_in[11];
    const float* p2w  = (const float*)d_in[12];
    const float* p2b  = (const float*)d_in[13];
    const float* pg1g = (const float*)d_in[14];
    const float* pg1b = (const float*)d_in[15];
    const float* pg2g = (const float*)d_in[16];
    const float* pg2b = (const float*)d_in[17];
    float* out = (float*)d_out;

    float* ws = (float*)d_ws;
    float* gridbuf  = ws;                       // 16777216 f: feat_sum -> grid -> out_grid (in place)
    float* conv1o   = gridbuf + 16777216;       // 16777216 f
    float* h1       = conv1o + 16777216;        // 16777216 f
    float* wsum     = h1 + 16777216;            // 262144 f
    float* wr1      = wsum + 262144;            // 110592 f
    float* wr2      = wr1 + 110592;             // 110592 f
    float* stats_p1 = wr2 + 110592;             // 1024 f each
    float* stats_v1 = stats_p1 + 1024;
    float* stats_v2 = stats_v1 + 1024;
    float* stats_p2 = stats_v2 + 1024;
    float* coef_p1  = stats_p2 + 1024;
    float* coef_v1  = coef_p1 + 1024;
    float* coef_v2  = coef_v1 + 1024;
    float* coef_p2  = coef_v2 + 1024;

    size_t needed = (size_t)(coef_p2 + 1024 - ws) * sizeof(float);
    if (ws_size < needed) return;  // scratch too small; bench will show as wrong output

    hipMemsetAsync(gridbuf, 0, (size_t)16777216 * 4, stream);
    hipMemsetAsync(wsum, 0, (size_t)262144 * 4, stream);
    hipMemsetAsync(stats_p1, 0, (size_t)4096 * 4, stream);  // all 4 stats sets contiguous

    k_reorder_w<<<432, 256, 0, stream>>>(conv1_w, conv2_w, wr1, wr2);
    k_voxelize<<<4096, 256, 0, stream>>>(points, features, gridbuf, wsum, stats_p1);
    k_coef<<<1, 512, 0, stream>>>(stats_p1, pg1g, pg1b, coef_p1);
    k_finalize<<<512, 256, 0, stream>>>(gridbuf, wsum, stats_v1);
    k_coef<<<1, 512, 0, stream>>>(stats_v1, g1_gamma, g1_beta, coef_v1);
    k_conv<<<2048, 256, 0, stream>>>(gridbuf, wr1, conv1_b, coef_v1, conv1o, stats_v2, nullptr, nullptr);
    k_coef<<<1, 512, 0, stream>>>(stats_v2, g2_gamma, g2_beta, coef_v2);
    k_conv<<<2048, 256, 0, stream>>>(conv1o, wr2, conv2_b, coef_v2, gridbuf, nullptr, gridbuf, coef_v1);
    k_point1<<<4096, 256, 0, stream>>>(features, p1w, p1b, coef_p1, h1, stats_p2);
    k_coef<<<1, 512, 0, stream>>>(stats_p2, pg2g, pg2b, coef_p2);
    k_final<<<4096, 256, 0, stream>>>(points, features, h1, p2w, p2b, coef_p1, coef_p2, gridbuf, out);
}

// Round 2
// 1015.196 us; speedup vs baseline: 3.8599x; 3.8599x over previous
//
#include <hip/hip_runtime.h>

// Problem constants
#define BB 8
#define NB 32768
#define RR 32
#define VV (32*32*32)
#define INV_SQRT2 0.70710678118654752440f

typedef __attribute__((ext_vector_type(8))) short s8v;      // 8 bf16 (MFMA A/B frag)
typedef __attribute__((ext_vector_type(8))) unsigned short u16x8;
typedef __attribute__((ext_vector_type(4))) float f4v;      // MFMA C/D frag

static __device__ __forceinline__ float lrelu(float x) { return x > 0.f ? x : 0.01f * x; }
static __device__ __forceinline__ float rl(float v, int i) {
    return __uint_as_float((unsigned)__builtin_amdgcn_readlane(__float_as_uint(v), i));
}
static __device__ __forceinline__ unsigned short f2bf(float x) {
    unsigned u = __float_as_uint(x);
    u += 0x7fff + ((u >> 16) & 1);          // RNE
    return (unsigned short)(u >> 16);
}

static __device__ __forceinline__ void corner_setup(float px, float py, float pz,
    int& c0x, int& c0y, int& c0z, int& c1x, int& c1y, int& c1z,
    float& fx, float& fy, float& fz)
{
    float cx = fminf(fmaxf(px, 0.f), 1.f) * 31.f;
    float cy = fminf(fmaxf(py, 0.f), 1.f) * 31.f;
    float cz = fminf(fmaxf(pz, 0.f), 1.f) * 31.f;
    float f0x = floorf(cx), f0y = floorf(cy), f0z = floorf(cz);
    c0x = (int)f0x; c0y = (int)f0y; c0z = (int)f0z;
    fx = cx - f0x; fy = cy - f0y; fz = cz - f0z;
    c1x = min(c0x + 1, 31); c1y = min(c0y + 1, 31); c1z = min(c0z + 1, 31);
}

// Reorder conv weights [O][I][3][3][3] f32 -> bf16 [conv][tap9][col=o][k=dz*64+i],
// pre-XOR-swizzled within each 384B col-row so LDS staging is a linear copy and
// swizzled ds_read_b128 at MFMA time is bank-conflict-free.
__global__ __launch_bounds__(256) void k_reorder_w(const float* __restrict__ w1,
                                                   const float* __restrict__ w2,
                                                   unsigned short* __restrict__ wrb)
{
    int idx = blockIdx.x * 256 + threadIdx.x;
    if (idx >= 2 * 9 * 64 * 192) return;
    int conv = idx / 110592; int r = idx - conv * 110592;
    int tap = r / 12288; r -= tap * 12288;
    int col = r / 192; int k = r - col * 192;
    int dz = k >> 6, i = k & 63;
    int dx = tap / 3, dy = tap - dx * 3;
    const float* w = conv ? w2 : w1;
    float v = w[(col * 64 + i) * 27 + (dx * 9 + dy * 3 + dz)];
    int kd = k ^ ((col & 7) << 3);          // ushort-index form of byte ^ ((col&7)<<4)
    wrb[conv * 110592 + tap * 12288 + col * 192 + kd] = f2bf(v);
}

// Trilinear scatter (atomics) + point-branch GN1 stats (sum, sumsq per channel).
__global__ __launch_bounds__(256) void k_voxelize(const float* __restrict__ pts,
                                                  const float* __restrict__ feat,
                                                  float* __restrict__ fsum,
                                                  float* __restrict__ wsum,
                                                  float* __restrict__ statsP)
{
    __shared__ float sred[256];
    const int b = blockIdx.x >> 9;
    const int n0 = (blockIdx.x & 511) * 64;
    const int wid = threadIdx.x >> 6, lane = threadIdx.x & 63;
    float s = 0.f, s2 = 0.f;
    for (int j = 0; j < 16; ++j) {
        const int base = b * NB + n0 + wid * 16 + j;
        const float f = feat[base * 64 + lane];
        s += f; s2 += f * f;
        const float px = pts[base * 3 + 0], py = pts[base * 3 + 1], pz = pts[base * 3 + 2];
        int c0x, c0y, c0z, c1x, c1y, c1z; float fx, fy, fz;
        corner_setup(px, py, pz, c0x, c0y, c0z, c1x, c1y, c1z, fx, fy, fz);
        const float w0x = 1.f - fx, w0y = 1.f - fy, w0z = 1.f - fz;
#pragma unroll
        for (int k = 0; k < 8; ++k) {
            const int cx = (k & 4) ? c1x : c0x;
            const int cy = (k & 2) ? c1y : c0y;
            const int cz = (k & 1) ? c1z : c0z;
            const float w = ((k & 4) ? fx : w0x) * ((k & 2) ? fy : w0y) * ((k & 1) ? fz : w0z);
            atomicAdd(&fsum[(b * VV + (cx * RR + cy) * RR + cz) * 64 + lane], w * f);
        }
        if (lane < 8) {
            const int cx = (lane & 4) ? c1x : c0x;
            const int cy = (lane & 2) ? c1y : c0y;
            const int cz = (lane & 1) ? c1z : c0z;
            const float w = ((lane & 4) ? fx : w0x) * ((lane & 2) ? fy : w0y) * ((lane & 1) ? fz : w0z);
            atomicAdd(&wsum[b * VV + (cx * RR + cy) * RR + cz], w);
        }
    }
    sred[threadIdx.x] = s; __syncthreads();
    if (threadIdx.x < 64) {
        float t = sred[threadIdx.x] + sred[threadIdx.x + 64] + sred[threadIdx.x + 128] + sred[threadIdx.x + 192];
        atomicAdd(&statsP[(b * 64 + threadIdx.x) * 2], t);
    }
    __syncthreads();
    sred[threadIdx.x] = s2; __syncthreads();
    if (threadIdx.x < 64) {
        float t = sred[threadIdx.x] + sred[threadIdx.x + 64] + sred[threadIdx.x + 128] + sred[threadIdx.x + 192];
        atomicAdd(&statsP[(b * 64 + threadIdx.x) * 2 + 1], t);
    }
}

// grid = fsum / max(wsum,1e-8) in place, + voxel GN1 stats.
__global__ __launch_bounds__(256) void k_finalize(float* __restrict__ g,
                                                  const float* __restrict__ wsum,
                                                  float* __restrict__ statsV)
{
    __shared__ float sred[256];
    const int b = blockIdx.x >> 6;
    const int v0 = (blockIdx.x & 63) * 512;
    const int wid = threadIdx.x >> 6, lane = threadIdx.x & 63;
    float s = 0.f, s2 = 0.f;
    for (int k = 0; k < 128; ++k) {
        const int vox = v0 + k * 4 + wid;
        const float w = wsum[b * VV + vox];
        const int idx = (b * VV + vox) * 64 + lane;
        const float val = g[idx] / fmaxf(w, 1e-8f);
        g[idx] = val;
        s += val; s2 += val * val;
    }
    sred[threadIdx.x] = s; __syncthreads();
    if (threadIdx.x < 64) {
        float t = sred[threadIdx.x] + sred[threadIdx.x + 64] + sred[threadIdx.x + 128] + sred[threadIdx.x + 192];
        atomicAdd(&statsV[(b * 64 + threadIdx.x) * 2], t);
    }
    __syncthreads();
    sred[threadIdx.x] = s2; __syncthreads();
    if (threadIdx.x < 64) {
        float t = sred[threadIdx.x] + sred[threadIdx.x + 64] + sred[threadIdx.x + 128] + sred[threadIdx.x + 192];
        atomicAdd(&statsV[(b * 64 + threadIdx.x) * 2 + 1], t);
    }
}

// stats -> per-channel affine (a,b): y = a*x + b implements groupnorm (groups of 2 ch x 32768).
__global__ void k_coef(const float* __restrict__ stats, const float* __restrict__ gamma,
                       const float* __restrict__ beta, float* __restrict__ coef)
{
    int tid = threadIdx.x;           // 512 threads: b=tid>>6, c=tid&63
    int b = tid >> 6, c = tid & 63, g = c >> 1;
    float s = stats[(b * 64 + 2 * g) * 2] + stats[(b * 64 + 2 * g + 1) * 2];
    float q = stats[(b * 64 + 2 * g) * 2 + 1] + stats[(b * 64 + 2 * g + 1) * 2 + 1];
    float mean = s / 65536.f;
    float var = q / 65536.f - mean * mean;
    float a = gamma[c] * rsqrtf(var + 1e-5f);
    coef[(b * 64 + c) * 2] = a;
    coef[(b * 64 + c) * 2 + 1] = beta[c] - mean * a;
}

// 3x3x3 conv C=64->64 SAME as bf16 implicit GEMM on MFMA.
// Block: 512 thr / 8 waves, tile = 2(x) x 4(y) x 32(z) = 256 voxels; wave w owns
// z-column (xi=w>>2, yi=w&3): M=32 x N=64 via 2x4 mfma_f32_16x16x32_bf16 frags.
// K per (dx,dy) tap = 192 (contiguous z-1..z+1 x 64ch window in channels-last layout).
// in_lds: padded halo [4px][6py][34pz][64ci] bf16, XOR-swizzled per z-row.
// w_lds: per-tap [64col][192k] bf16, staged linearly from pre-swizzled global.
__global__ __launch_bounds__(512) void k_conv_mfma(const float* __restrict__ in,
                                                   const unsigned short* __restrict__ wrb,
                                                   const float* __restrict__ bias,
                                                   const float* __restrict__ coef_in,
                                                   float* out,
                                                   float* __restrict__ statsOut,
                                                   const float* resid,
                                                   const float* __restrict__ coef_res)
{
    extern __shared__ char smem[];
    unsigned short* in_lds = (unsigned short*)smem;                 // 52224 ushort = 104448 B
    unsigned short* w_lds  = (unsigned short*)(smem + 104448);      // 12288 ushort = 24576 B
    float* ca    = (float*)(smem + 129024);                         // 64
    float* cb    = ca + 64;                                         // 64
    float* sstat = cb + 64;                                         // 128

    const int b = blockIdx.x >> 7;
    const int tile = blockIdx.x & 127;
    const int x0 = (tile >> 3) * 2, y0 = (tile & 7) * 4;
    const int tid = threadIdx.x;

    if (tid < 64) {
        ca[tid] = coef_in[(b * 64 + tid) * 2];
        cb[tid] = coef_in[(b * 64 + tid) * 2 + 1];
    }
    if (tid < 128) sstat[tid] = 0.f;
    __syncthreads();

    // ---- stage input halo (affine+lrelu+cvt fused), swizzled ds_write_b128 ----
    for (int g = tid; g < 6528; g += 512) {           // 816 rows x 8 granules
        int row = g >> 3, s = g & 7;
        int px = row / 204;                            // 6*34
        int rem = row - px * 204;
        int py = rem / 34;
        int pz = rem - py * 34;
        int gx = x0 + px - 1, gy = y0 + py - 1, gz = pz - 1;
        int byteoff = row * 128 + ((s * 16) ^ ((pz & 7) << 4));
        u16x8* dst = (u16x8*)((char*)in_lds + byteoff);
        u16x8 o;
        if ((unsigned)gx < 32u && (unsigned)gy < 32u && (unsigned)gz < 32u) {
            const float* src = &in[(b * VV + (gx * RR + gy) * RR + gz) * 64 + s * 8];
            float4 v0 = *(const float4*)src;
            float4 v1 = *(const float4*)(src + 4);
            float xs[8] = {v0.x, v0.y, v0.z, v0.w, v1.x, v1.y, v1.z, v1.w};
            int ci = s * 8;
#pragma unroll
            for (int q = 0; q < 8; ++q) {
                float t = fmaf(ca[ci + q], xs[q], cb[ci + q]);
                o[q] = f2bf(lrelu(t));
            }
        } else {
            o = (u16x8)0;
        }
        *dst = o;
    }

    const int w = tid >> 6, l = tid & 63;
    const int l15 = l & 15, lq = l >> 4;
    const int xi = w >> 2, yi = w & 3;
    const int bxor = (l & 7) << 4;

    f4v acc[2][4];
#pragma unroll
    for (int nt = 0; nt < 4; ++nt) {
        float bv = bias[nt * 16 + l15];
        f4v bf = {bv, bv, bv, bv};
        acc[0][nt] = bf; acc[1][nt] = bf;
    }

    for (int tap = 0; tap < 9; ++tap) {
        __syncthreads();
        {   // stage this tap's weights: linear 48B/thread copy (pre-swizzled global)
            const unsigned short* src = wrb + tap * 12288 + tid * 24;
            u16x8* d = (u16x8*)(w_lds + tid * 24);
            u16x8 a0 = *(const u16x8*)src;
            u16x8 a1 = *(const u16x8*)(src + 8);
            u16x8 a2 = *(const u16x8*)(src + 16);
            d[0] = a0; d[1] = a1; d[2] = a2;
        }
        __syncthreads();
        const int dx = tap / 3, dy = tap - dx * 3;
        const int rowbase = ((xi + dx) * 6 + (yi + dy)) * 34;
#pragma unroll
        for (int ks = 0; ks < 6; ++ks) {
            const int dz = ks >> 1, cib = (ks & 1) * 32;
            s8v a0, a1;
            {
                int pz = l15 + dz;
                int boff = (rowbase + pz) * 128 + (((cib + lq * 8) * 2) ^ ((pz & 7) << 4));
                a0 = *(const s8v*)((const char*)in_lds + boff);
            }
            {
                int pz = 16 + l15 + dz;
                int boff = (rowbase + pz) * 128 + (((cib + lq * 8) * 2) ^ ((pz & 7) << 4));
                a1 = *(const s8v*)((const char*)in_lds + boff);
            }
#pragma unroll
            for (int nt = 0; nt < 4; ++nt) {
                int boff = (nt * 16 + l15) * 384 + ((ks * 64 + lq * 16) ^ bxor);
                s8v bf = *(const s8v*)((const char*)w_lds + boff);
                acc[0][nt] = __builtin_amdgcn_mfma_f32_16x16x32_bf16(a0, bf, acc[0][nt], 0, 0, 0);
                acc[1][nt] = __builtin_amdgcn_mfma_f32_16x16x32_bf16(a1, bf, acc[1][nt], 0, 0, 0);
            }
        }
    }

    // ---- epilogue ----
    const int outb = (b * VV + ((x0 + xi) * RR + (y0 + yi)) * RR) * 64;
    if (!resid) {
        // conv1: store raw output + GN2 stats
        float sa[4] = {0, 0, 0, 0}, sq[4] = {0, 0, 0, 0};
#pragma unroll
        for (int m = 0; m < 2; ++m)
#pragma unroll
            for (int nt = 0; nt < 4; ++nt)
#pragma unroll
                for (int j = 0; j < 4; ++j) {
                    int z = m * 16 + lq * 4 + j;
                    float v = acc[m][nt][j];
                    out[outb + z * 64 + nt * 16 + l15] = v;
                    sa[nt] += v; sq[nt] += v * v;
                }
#pragma unroll
        for (int nt = 0; nt < 4; ++nt) {
            float a = sa[nt], q = sq[nt];
            a += __shfl_xor(a, 16); q += __shfl_xor(q, 16);
            a += __shfl_xor(a, 32); q += __shfl_xor(q, 32);
            if (lq == 0) {
                atomicAdd(&sstat[(nt * 16 + l15) * 2], a);
                atomicAdd(&sstat[(nt * 16 + l15) * 2 + 1], q);
            }
        }
        __syncthreads();
        if (tid < 128) atomicAdd(&statsOut[b * 128 + tid], sstat[tid]);
    } else {
        // conv2: out = (conv + affine(resid)) / sqrt2, in place over resid
#pragma unroll
        for (int nt = 0; nt < 4; ++nt) {
            int ch = nt * 16 + l15;
            float a2 = coef_res[(b * 64 + ch) * 2];
            float b2 = coef_res[(b * 64 + ch) * 2 + 1];
#pragma unroll
            for (int m = 0; m < 2; ++m)
#pragma unroll
                for (int j = 0; j < 4; ++j) {
                    int z = m * 16 + lq * 4 + j;
                    int idx = outb + z * 64 + ch;
                    float r = resid[idx];
                    out[idx] = (acc[m][nt][j] + fmaf(a2, r, b2)) * INV_SQRT2;
                }
        }
    }
}

// Point branch conv1x1 #1: h = W @ lrelu(gn1(f)) + bias, + GN2 stats.
__global__ __launch_bounds__(256) void k_point1(const float* __restrict__ feat,
                                                const float* __restrict__ W,
                                                const float* __restrict__ bias,
                                                const float* __restrict__ coefP,
                                                float* __restrict__ h1out,
                                                float* __restrict__ statsOut)
{
    __shared__ float w_lds[64 * 65];
    __shared__ float sred[256];
    const int b = blockIdx.x >> 9;
    const int n0 = (blockIdx.x & 511) * 64;
    const int wid = threadIdx.x >> 6, lane = threadIdx.x & 63;
    for (int k = threadIdx.x; k < 4096; k += 256)
        w_lds[(k & 63) * 65 + (k >> 6)] = W[k];   // w_lds[i][o] = W[o][i]
    __syncthreads();
    float wreg[64];
#pragma unroll
    for (int i = 0; i < 64; ++i) wreg[i] = w_lds[i * 65 + lane];
    const float bo = bias[lane];
    const float a = coefP[(b * 64 + lane) * 2], bb = coefP[(b * 64 + lane) * 2 + 1];
    float s = 0.f, s2 = 0.f;
    for (int j = 0; j < 16; ++j) {
        const int base = b * NB + n0 + wid * 16 + j;
        const float f = feat[base * 64 + lane];
        const float act = lrelu(a * f + bb);
        float o = bo;
#pragma unroll
        for (int i = 0; i < 64; ++i) o += rl(act, i) * wreg[i];
        h1out[base * 64 + lane] = o;
        s += o; s2 += o * o;
    }
    sred[threadIdx.x] = s; __syncthreads();
    if (threadIdx.x < 64) {
        float t = sred[threadIdx.x] + sred[threadIdx.x + 64] + sred[threadIdx.x + 128] + sred[threadIdx.x + 192];
        atomicAdd(&statsOut[(b * 64 + threadIdx.x) * 2], t);
    }
    __syncthreads();
    sred[threadIdx.x] = s2; __syncthreads();
    if (threadIdx.x < 64) {
        float t = sred[threadIdx.x] + sred[threadIdx.x + 64] + sred[threadIdx.x + 128] + sred[threadIdx.x + 192];
        atomicAdd(&statsOut[(b * 64 + threadIdx.x) * 2 + 1], t);
    }
}

// Final fused: point conv1x1 #2 + point residual + trilinear devox gather + output mix.
__global__ __launch_bounds__(256) void k_final(const float* __restrict__ pts,
                                               const float* __restrict__ feat,
                                               const float* __restrict__ h1,
                                               const float* __restrict__ W2,
                                               const float* __restrict__ bias2,
                                               const float* __restrict__ coefP1,
                                               const float* __restrict__ coefP2,
                                               const float* __restrict__ outg,
                                               float* __restrict__ out)
{
    __shared__ float w_lds[64 * 65];
    const int b = blockIdx.x >> 9;
    const int n0 = (blockIdx.x & 511) * 64;
    const int wid = threadIdx.x >> 6, lane = threadIdx.x & 63;
    for (int k = threadIdx.x; k < 4096; k += 256)
        w_lds[(k & 63) * 65 + (k >> 6)] = W2[k];
    __syncthreads();
    float wreg[64];
#pragma unroll
    for (int i = 0; i < 64; ++i) wreg[i] = w_lds[i * 65 + lane];
    const float bo = bias2[lane];
    const float a1 = coefP1[(b * 64 + lane) * 2], b1 = coefP1[(b * 64 + lane) * 2 + 1];
    const float a2 = coefP2[(b * 64 + lane) * 2], b2 = coefP2[(b * 64 + lane) * 2 + 1];
    for (int j = 0; j < 16; ++j) {
        const int base = b * NB + n0 + wid * 16 + j;
        const float f = feat[base * 64 + lane];
        const float fn = a1 * f + b1;
        const float act = lrelu(a2 * h1[base * 64 + lane] + b2);
        float o = bo;
#pragma unroll
        for (int i = 0; i < 64; ++i) o += rl(act, i) * wreg[i];
        const float ptsv = (o + fn) * INV_SQRT2;
        const float px = pts[base * 3 + 0], py = pts[base * 3 + 1], pz = pts[base * 3 + 2];
        int c0x, c0y, c0z, c1x, c1y, c1z; float fx, fy, fz;
        corner_setup(px, py, pz, c0x, c0y, c0z, c1x, c1y, c1z, fx, fy, fz);
        const float w0x = 1.f - fx, w0y = 1.f - fy, w0z = 1.f - fz;
        float dv = 0.f;
#pragma unroll
        for (int k = 0; k < 8; ++k) {
            const int cx = (k & 4) ? c1x : c0x;
            const int cy = (k & 2) ? c1y : c0y;
            const int cz = (k & 1) ? c1z : c0z;
            const float w = ((k & 4) ? fx : w0x) * ((k & 2) ? fy : w0y) * ((k & 1) ? fz : w0z);
            dv += w * outg[(b * VV + (cx * RR + cy) * RR + cz) * 64 + lane];
        }
        out[base * 64 + lane] = (ptsv + dv) * INV_SQRT2;
    }
}

extern "C" void kernel_launch(void* const* d_in, const int* in_sizes, int n_in,
                              void* d_out, int out_size, void* d_ws, size_t ws_size,
                              hipStream_t stream)
{
    const float* points   = (const float*)d_in[0];
    const float* features = (const float*)d_in[1];
    const float* conv1_w  = (const float*)d_in[2];
    const float* conv1_b  = (const float*)d_in[3];
    const float* conv2_w  = (const float*)d_in[4];
    const float* conv2_b  = (const float*)d_in[5];
    const float* g1_gamma = (const float*)d_in[6];
    const float* g1_beta  = (const float*)d_in[7];
    const float* g2_gamma = (const float*)d_in[8];
    const float* g2_beta  = (const float*)d_in[9];
    const float* p1w  = (const float*)d_in[10];
    const float* p1b  = (const float*)d_in[11];
    const float* p2w  = (const float*)d_in[12];
    const float* p2b  = (const float*)d_in[13];
    const float* pg1g = (const float*)d_in[14];
    const float* pg1b = (const float*)d_in[15];
    const float* pg2g = (const float*)d_in[16];
    const float* pg2b = (const float*)d_in[17];
    float* out = (float*)d_out;

    float* ws = (float*)d_ws;
    float* gridbuf  = ws;                       // 16777216 f: feat_sum -> grid -> out_grid (in place)
    float* conv1o   = gridbuf + 16777216;       // 16777216 f
    float* h1       = conv1o + 16777216;        // 16777216 f
    float* wsum     = h1 + 16777216;            // 262144 f
    unsigned short* wrb = (unsigned short*)(wsum + 262144);  // 221184 ushort = 110592 f
    float* stats_p1 = wsum + 262144 + 110592;   // 1024 f each
    float* stats_v1 = stats_p1 + 1024;
    float* stats_v2 = stats_v1 + 1024;
    float* stats_p2 = stats_v2 + 1024;
    float* coef_p1  = stats_p2 + 1024;
    float* coef_v1  = coef_p1 + 1024;
    float* coef_v2  = coef_v1 + 1024;
    float* coef_p2  = coef_v2 + 1024;

    size_t needed = (size_t)(coef_p2 + 1024 - ws) * sizeof(float);
    if (ws_size < needed) return;

    hipMemsetAsync(gridbuf, 0, (size_t)16777216 * 4, stream);
    hipMemsetAsync(wsum, 0, (size_t)262144 * 4, stream);
    hipMemsetAsync(stats_p1, 0, (size_t)4096 * 4, stream);  // all 4 stats sets contiguous

    const size_t conv_lds = 104448 + 24576 + 512 + 512;      // 130048 B

    k_reorder_w<<<864, 256, 0, stream>>>(conv1_w, conv2_w, wrb);
    k_voxelize<<<4096, 256, 0, stream>>>(points, features, gridbuf, wsum, stats_p1);
    k_coef<<<1, 512, 0, stream>>>(stats_p1, pg1g, pg1b, coef_p1);
    k_finalize<<<512, 256, 0, stream>>>(gridbuf, wsum, stats_v1);
    k_coef<<<1, 512, 0, stream>>>(stats_v1, g1_gamma, g1_beta, coef_v1);
    k_conv_mfma<<<1024, 512, conv_lds, stream>>>(gridbuf, wrb, conv1_b, coef_v1,
                                                 conv1o, stats_v2, nullptr, nullptr);
    k_coef<<<1, 512, 0, stream>>>(stats_v2, g2_gamma, g2_beta, coef_v2);
    k_conv_mfma<<<1024, 512, conv_lds, stream>>>(conv1o, wrb + 110592, conv2_b, coef_v2,
                                                 gridbuf, nullptr, gridbuf, coef_v1);
    k_point1<<<4096, 256, 0, stream>>>(features, p1w, p1b, coef_p1, h1, stats_p2);
    k_coef<<<1, 512, 0, stream>>>(stats_p2, pg2g, pg2b, coef_p2);
    k_final<<<4096, 256, 0, stream>>>(points, features, h1, p2w, p2b, coef_p1, coef_p2, gridbuf, out);
}

// Round 3
// 823.389 us; speedup vs baseline: 4.7591x; 1.2329x over previous
//
#include <hip/hip_runtime.h>

// Problem constants
#define BB 8
#define NB 32768
#define RR 32
#define VV (32*32*32)
#define TOTAL_PAIRS (BB*NB*8)          // 2097152
#define INV_SQRT2 0.70710678118654752440f

typedef __attribute__((ext_vector_type(8))) short s8v;      // 8 bf16 (MFMA A/B frag)
typedef __attribute__((ext_vector_type(8))) unsigned short u16x8;
typedef __attribute__((ext_vector_type(4))) float f4v;      // MFMA C/D frag

static __device__ __forceinline__ float lrelu(float x) { return x > 0.f ? x : 0.01f * x; }
static __device__ __forceinline__ float rl(float v, int i) {
    return __uint_as_float((unsigned)__builtin_amdgcn_readlane(__float_as_uint(v), i));
}
static __device__ __forceinline__ unsigned short f2bf(float x) {
    unsigned u = __float_as_uint(x);
    u += 0x7fff + ((u >> 16) & 1);          // RNE
    return (unsigned short)(u >> 16);
}

static __device__ __forceinline__ void corner_setup(float px, float py, float pz,
    int& c0x, int& c0y, int& c0z, int& c1x, int& c1y, int& c1z,
    float& fx, float& fy, float& fz)
{
    float cx = fminf(fmaxf(px, 0.f), 1.f) * 31.f;
    float cy = fminf(fmaxf(py, 0.f), 1.f) * 31.f;
    float cz = fminf(fmaxf(pz, 0.f), 1.f) * 31.f;
    float f0x = floorf(cx), f0y = floorf(cy), f0z = floorf(cz);
    c0x = (int)f0x; c0y = (int)f0y; c0z = (int)f0z;
    fx = cx - f0x; fy = cy - f0y; fz = cz - f0z;
    c1x = min(c0x + 1, 31); c1y = min(c0y + 1, 31); c1z = min(c0z + 1, 31);
}

// Reorder conv weights [O][I][3][3][3] f32 -> bf16 [conv][tap9][col=o][k=dz*64+i],
// pre-XOR-swizzled within each 384B col-row so LDS staging is a linear copy and
// swizzled ds_read_b128 at MFMA time is bank-conflict-free.
__global__ __launch_bounds__(256) void k_reorder_w(const float* __restrict__ w1,
                                                   const float* __restrict__ w2,
                                                   unsigned short* __restrict__ wrb)
{
    int idx = blockIdx.x * 256 + threadIdx.x;
    if (idx >= 2 * 9 * 64 * 192) return;
    int conv = idx / 110592; int r = idx - conv * 110592;
    int tap = r / 12288; r -= tap * 12288;
    int col = r / 192; int k = r - col * 192;
    int dz = k >> 6, i = k & 63;
    int dx = tap / 3, dy = tap - dx * 3;
    const float* w = conv ? w2 : w1;
    float v = w[(col * 64 + i) * 27 + (dx * 9 + dy * 3 + dz)];
    int kd = k ^ ((col & 7) << 3);          // ushort-index form of byte ^ ((col&7)<<4)
    wrb[conv * 110592 + tap * 12288 + col * 192 + kd] = f2bf(v);
}

// Phase A: count (voxel,corner) pairs per voxel + point-branch GN1 stats.
__global__ __launch_bounds__(256) void k_count(const float* __restrict__ pts,
                                               const float* __restrict__ feat,
                                               unsigned* __restrict__ cnt,
                                               float* __restrict__ statsP)
{
    __shared__ float sred[256];
    const int b = blockIdx.x >> 9;
    const int n0 = (blockIdx.x & 511) * 64;
    const int wid = threadIdx.x >> 6, lane = threadIdx.x & 63;
    float s = 0.f, s2 = 0.f;
    for (int j = 0; j < 16; ++j) {
        const int base = b * NB + n0 + wid * 16 + j;
        const float f = feat[base * 64 + lane];
        s += f; s2 += f * f;
        const float px = pts[base * 3 + 0], py = pts[base * 3 + 1], pz = pts[base * 3 + 2];
        int c0x, c0y, c0z, c1x, c1y, c1z; float fx, fy, fz;
        corner_setup(px, py, pz, c0x, c0y, c0z, c1x, c1y, c1z, fx, fy, fz);
        if (lane < 8) {
            const int cx = (lane & 4) ? c1x : c0x;
            const int cy = (lane & 2) ? c1y : c0y;
            const int cz = (lane & 1) ? c1z : c0z;
            atomicAdd(&cnt[b * VV + (cx * RR + cy) * RR + cz], 1u);
        }
    }
    sred[threadIdx.x] = s; __syncthreads();
    if (threadIdx.x < 64) {
        float t = sred[threadIdx.x] + sred[threadIdx.x + 64] + sred[threadIdx.x + 128] + sred[threadIdx.x + 192];
        atomicAdd(&statsP[(b * 64 + threadIdx.x) * 2], t);
    }
    __syncthreads();
    sred[threadIdx.x] = s2; __syncthreads();
    if (threadIdx.x < 64) {
        float t = sred[threadIdx.x] + sred[threadIdx.x + 64] + sred[threadIdx.x + 128] + sred[threadIdx.x + 192];
        atomicAdd(&statsP[(b * 64 + threadIdx.x) * 2 + 1], t);
    }
}

// Scan step 1: per-block (1024 counts) exclusive scan; emit block totals.
__global__ __launch_bounds__(256) void k_scan1(const unsigned* __restrict__ cnt,
                                               unsigned* __restrict__ start,
                                               unsigned* __restrict__ bsum)
{
    __shared__ unsigned sd[256];
    const int t = threadIdx.x;
    const uint4 c = ((const uint4*)cnt)[blockIdx.x * 256 + t];
    unsigned tsum = c.x + c.y + c.z + c.w;
    sd[t] = tsum; __syncthreads();
    for (int off = 1; off < 256; off <<= 1) {
        unsigned x = (t >= off) ? sd[t - off] : 0u;
        __syncthreads();
        sd[t] += x;
        __syncthreads();
    }
    unsigned excl = (t == 0) ? 0u : sd[t - 1];
    uint4 o;
    o.x = excl; o.y = excl + c.x; o.z = o.y + c.y; o.w = o.z + c.z;
    ((uint4*)start)[blockIdx.x * 256 + t] = o;
    if (t == 255) bsum[blockIdx.x] = sd[255];
}

// Scan step 2: exclusive scan of 256 block sums.
__global__ void k_scan2(const unsigned* __restrict__ bsum, unsigned* __restrict__ boff)
{
    __shared__ unsigned sd[256];
    const int t = threadIdx.x;
    sd[t] = bsum[t]; __syncthreads();
    for (int off = 1; off < 256; off <<= 1) {
        unsigned x = (t >= off) ? sd[t - off] : 0u;
        __syncthreads();
        sd[t] += x;
        __syncthreads();
    }
    boff[t] = (t == 0) ? 0u : sd[t - 1];
}

// Scan step 3: add block offsets; also produce the working cursor copy.
__global__ __launch_bounds__(256) void k_scan3(unsigned* __restrict__ start,
                                               const unsigned* __restrict__ boff,
                                               unsigned* __restrict__ cur)
{
    const int g = blockIdx.x * 256 + threadIdx.x;
    const unsigned o = boff[blockIdx.x];
    uint4 v = ((uint4*)start)[g];
    v.x += o; v.y += o; v.z += o; v.w += o;
    ((uint4*)start)[g] = v;
    ((uint4*)cur)[g] = v;
}

// Phase C: write (point, weight) pairs into per-voxel segments.
__global__ __launch_bounds__(256) void k_fill(const float* __restrict__ pts,
                                              unsigned* __restrict__ cur,
                                              uint2* __restrict__ pairs)
{
    const int p = blockIdx.x * 256 + threadIdx.x;   // global point id
    const float px = pts[p * 3 + 0], py = pts[p * 3 + 1], pz = pts[p * 3 + 2];
    int c0x, c0y, c0z, c1x, c1y, c1z; float fx, fy, fz;
    corner_setup(px, py, pz, c0x, c0y, c0z, c1x, c1y, c1z, fx, fy, fz);
    const float w0x = 1.f - fx, w0y = 1.f - fy, w0z = 1.f - fz;
    const int bvv = (p >> 15) * VV;
#pragma unroll
    for (int k = 0; k < 8; ++k) {
        const int cx = (k & 4) ? c1x : c0x;
        const int cy = (k & 2) ? c1y : c0y;
        const int cz = (k & 1) ? c1z : c0z;
        const float w = ((k & 4) ? fx : w0x) * ((k & 2) ? fy : w0y) * ((k & 1) ? fz : w0z);
        unsigned slot = atomicAdd(&cur[bvv + (cx * RR + cy) * RR + cz], 1u);
        pairs[slot] = make_uint2((unsigned)p, __float_as_uint(w));
    }
}

// Phase D: per-voxel gather + normalize + voxel GN1 stats (replaces scatter+finalize).
__global__ __launch_bounds__(256) void k_gather(const uint2* __restrict__ pairs,
                                                const unsigned* __restrict__ start,
                                                const float* __restrict__ feat,
                                                float* __restrict__ grid,
                                                float* __restrict__ statsV)
{
    __shared__ float sred[256];
    const int tid = threadIdx.x, wid = tid >> 6, lane = tid & 63;
    const int vbase = blockIdx.x * 128 + wid * 32;
    const int b = blockIdx.x >> 8;
    float s = 0.f, s2 = 0.f;
    for (int i = 0; i < 32; ++i) {
        const int v = vbase + i;
        const int p0 = start[v];
        const int p1 = (v == BB * VV - 1) ? TOTAL_PAIRS : (int)start[v + 1];
        float acc = 0.f, wsum = 0.f;
        for (int base = p0; base < p1; base += 64) {
            uint2 pr = make_uint2(0u, 0u);
            if (base + lane < p1) pr = pairs[base + lane];
            const int m = min(64, p1 - base);
            int j = 0;
            for (; j + 3 < m; j += 4) {
                unsigned u0 = (unsigned)__builtin_amdgcn_readlane((int)pr.x, j);
                unsigned u1 = (unsigned)__builtin_amdgcn_readlane((int)pr.x, j + 1);
                unsigned u2 = (unsigned)__builtin_amdgcn_readlane((int)pr.x, j + 2);
                unsigned u3 = (unsigned)__builtin_amdgcn_readlane((int)pr.x, j + 3);
                float w0 = __uint_as_float((unsigned)__builtin_amdgcn_readlane((int)pr.y, j));
                float w1 = __uint_as_float((unsigned)__builtin_amdgcn_readlane((int)pr.y, j + 1));
                float w2 = __uint_as_float((unsigned)__builtin_amdgcn_readlane((int)pr.y, j + 2));
                float w3 = __uint_as_float((unsigned)__builtin_amdgcn_readlane((int)pr.y, j + 3));
                float f0 = feat[(size_t)u0 * 64 + lane];
                float f1 = feat[(size_t)u1 * 64 + lane];
                float f2 = feat[(size_t)u2 * 64 + lane];
                float f3 = feat[(size_t)u3 * 64 + lane];
                acc = fmaf(w0, f0, acc); acc = fmaf(w1, f1, acc);
                acc = fmaf(w2, f2, acc); acc = fmaf(w3, f3, acc);
                wsum += w0 + w1 + w2 + w3;
            }
            for (; j < m; ++j) {
                unsigned u0 = (unsigned)__builtin_amdgcn_readlane((int)pr.x, j);
                float w0 = __uint_as_float((unsigned)__builtin_amdgcn_readlane((int)pr.y, j));
                acc = fmaf(w0, feat[(size_t)u0 * 64 + lane], acc);
                wsum += w0;
            }
        }
        const float val = acc / fmaxf(wsum, 1e-8f);
        grid[(size_t)v * 64 + lane] = val;
        s += val; s2 += val * val;
    }
    sred[tid] = s; __syncthreads();
    if (tid < 64) {
        float t = sred[tid] + sred[tid + 64] + sred[tid + 128] + sred[tid + 192];
        atomicAdd(&statsV[(b * 64 + tid) * 2], t);
    }
    __syncthreads();
    sred[tid] = s2; __syncthreads();
    if (tid < 64) {
        float t = sred[tid] + sred[tid + 64] + sred[tid + 128] + sred[tid + 192];
        atomicAdd(&statsV[(b * 64 + tid) * 2 + 1], t);
    }
}

// stats -> per-channel affine (a,b): y = a*x + b implements groupnorm (groups of 2 ch x 32768).
__global__ void k_coef(const float* __restrict__ stats, const float* __restrict__ gamma,
                       const float* __restrict__ beta, float* __restrict__ coef)
{
    int tid = threadIdx.x;           // 512 threads: b=tid>>6, c=tid&63
    int b = tid >> 6, c = tid & 63, g = c >> 1;
    float s = stats[(b * 64 + 2 * g) * 2] + stats[(b * 64 + 2 * g + 1) * 2];
    float q = stats[(b * 64 + 2 * g) * 2 + 1] + stats[(b * 64 + 2 * g + 1) * 2 + 1];
    float mean = s / 65536.f;
    float var = q / 65536.f - mean * mean;
    float a = gamma[c] * rsqrtf(var + 1e-5f);
    coef[(b * 64 + c) * 2] = a;
    coef[(b * 64 + c) * 2 + 1] = beta[c] - mean * a;
}

// 3x3x3 conv C=64->64 SAME as bf16 implicit GEMM on MFMA.
__global__ __launch_bounds__(512) void k_conv_mfma(const float* __restrict__ in,
                                                   const unsigned short* __restrict__ wrb,
                                                   const float* __restrict__ bias,
                                                   const float* __restrict__ coef_in,
                                                   float* out,
                                                   float* __restrict__ statsOut,
                                                   const float* resid,
                                                   const float* __restrict__ coef_res)
{
    extern __shared__ char smem[];
    unsigned short* in_lds = (unsigned short*)smem;                 // 52224 ushort = 104448 B
    unsigned short* w_lds  = (unsigned short*)(smem + 104448);      // 12288 ushort = 24576 B
    float* ca    = (float*)(smem + 129024);                         // 64
    float* cb    = ca + 64;                                         // 64
    float* sstat = cb + 64;                                         // 128

    const int b = blockIdx.x >> 7;
    const int tile = blockIdx.x & 127;
    const int x0 = (tile >> 3) * 2, y0 = (tile & 7) * 4;
    const int tid = threadIdx.x;

    if (tid < 64) {
        ca[tid] = coef_in[(b * 64 + tid) * 2];
        cb[tid] = coef_in[(b * 64 + tid) * 2 + 1];
    }
    if (tid < 128) sstat[tid] = 0.f;
    __syncthreads();

    // ---- stage input halo (affine+lrelu+cvt fused), swizzled ds_write_b128 ----
    for (int g = tid; g < 6528; g += 512) {           // 816 rows x 8 granules
        int row = g >> 3, s = g & 7;
        int px = row / 204;                            // 6*34
        int rem = row - px * 204;
        int py = rem / 34;
        int pz = rem - py * 34;
        int gx = x0 + px - 1, gy = y0 + py - 1, gz = pz - 1;
        int byteoff = row * 128 + ((s * 16) ^ ((pz & 7) << 4));
        u16x8* dst = (u16x8*)((char*)in_lds + byteoff);
        u16x8 o;
        if ((unsigned)gx < 32u && (unsigned)gy < 32u && (unsigned)gz < 32u) {
            const float* src = &in[(b * VV + (gx * RR + gy) * RR + gz) * 64 + s * 8];
            float4 v0 = *(const float4*)src;
            float4 v1 = *(const float4*)(src + 4);
            float xs[8] = {v0.x, v0.y, v0.z, v0.w, v1.x, v1.y, v1.z, v1.w};
            int ci = s * 8;
#pragma unroll
            for (int q = 0; q < 8; ++q) {
                float t = fmaf(ca[ci + q], xs[q], cb[ci + q]);
                o[q] = f2bf(lrelu(t));
            }
        } else {
            o = (u16x8)0;
        }
        *dst = o;
    }

    const int w = tid >> 6, l = tid & 63;
    const int l15 = l & 15, lq = l >> 4;
    const int xi = w >> 2, yi = w & 3;
    const int bxor = (l & 7) << 4;

    f4v acc[2][4];
#pragma unroll
    for (int nt = 0; nt < 4; ++nt) {
        float bv = bias[nt * 16 + l15];
        f4v bf = {bv, bv, bv, bv};
        acc[0][nt] = bf; acc[1][nt] = bf;
    }

    for (int tap = 0; tap < 9; ++tap) {
        __syncthreads();
        {   // stage this tap's weights: linear 48B/thread copy (pre-swizzled global)
            const unsigned short* src = wrb + tap * 12288 + tid * 24;
            u16x8* d = (u16x8*)(w_lds + tid * 24);
            u16x8 a0 = *(const u16x8*)src;
            u16x8 a1 = *(const u16x8*)(src + 8);
            u16x8 a2 = *(const u16x8*)(src + 16);
            d[0] = a0; d[1] = a1; d[2] = a2;
        }
        __syncthreads();
        const int dx = tap / 3, dy = tap - dx * 3;
        const int rowbase = ((xi + dx) * 6 + (yi + dy)) * 34;
#pragma unroll
        for (int ks = 0; ks < 6; ++ks) {
            const int dz = ks >> 1, cib = (ks & 1) * 32;
            s8v a0, a1;
            {
                int pz = l15 + dz;
                int boff = (rowbase + pz) * 128 + (((cib + lq * 8) * 2) ^ ((pz & 7) << 4));
                a0 = *(const s8v*)((const char*)in_lds + boff);
            }
            {
                int pz = 16 + l15 + dz;
                int boff = (rowbase + pz) * 128 + (((cib + lq * 8) * 2) ^ ((pz & 7) << 4));
                a1 = *(const s8v*)((const char*)in_lds + boff);
            }
#pragma unroll
            for (int nt = 0; nt < 4; ++nt) {
                int boff = (nt * 16 + l15) * 384 + ((ks * 64 + lq * 16) ^ bxor);
                s8v bf = *(const s8v*)((const char*)w_lds + boff);
                acc[0][nt] = __builtin_amdgcn_mfma_f32_16x16x32_bf16(a0, bf, acc[0][nt], 0, 0, 0);
                acc[1][nt] = __builtin_amdgcn_mfma_f32_16x16x32_bf16(a1, bf, acc[1][nt], 0, 0, 0);
            }
        }
    }

    // ---- epilogue ----
    const int outb = (b * VV + ((x0 + xi) * RR + (y0 + yi)) * RR) * 64;
    if (!resid) {
        // conv1: store raw output + GN2 stats
        float sa[4] = {0, 0, 0, 0}, sq[4] = {0, 0, 0, 0};
#pragma unroll
        for (int m = 0; m < 2; ++m)
#pragma unroll
            for (int nt = 0; nt < 4; ++nt)
#pragma unroll
                for (int j = 0; j < 4; ++j) {
                    int z = m * 16 + lq * 4 + j;
                    float v = acc[m][nt][j];
                    out[outb + z * 64 + nt * 16 + l15] = v;
                    sa[nt] += v; sq[nt] += v * v;
                }
#pragma unroll
        for (int nt = 0; nt < 4; ++nt) {
            float a = sa[nt], q = sq[nt];
            a += __shfl_xor(a, 16); q += __shfl_xor(q, 16);
            a += __shfl_xor(a, 32); q += __shfl_xor(q, 32);
            if (lq == 0) {
                atomicAdd(&sstat[(nt * 16 + l15) * 2], a);
                atomicAdd(&sstat[(nt * 16 + l15) * 2 + 1], q);
            }
        }
        __syncthreads();
        if (tid < 128) atomicAdd(&statsOut[b * 128 + tid], sstat[tid]);
    } else {
        // conv2: out = (conv + affine(resid)) / sqrt2, in place over resid
#pragma unroll
        for (int nt = 0; nt < 4; ++nt) {
            int ch = nt * 16 + l15;
            float a2 = coef_res[(b * 64 + ch) * 2];
            float b2 = coef_res[(b * 64 + ch) * 2 + 1];
#pragma unroll
            for (int m = 0; m < 2; ++m)
#pragma unroll
                for (int j = 0; j < 4; ++j) {
                    int z = m * 16 + lq * 4 + j;
                    int idx = outb + z * 64 + ch;
                    float r = resid[idx];
                    out[idx] = (acc[m][nt][j] + fmaf(a2, r, b2)) * INV_SQRT2;
                }
        }
    }
}

// Point branch conv1x1 #1: h = W @ lrelu(gn1(f)) + bias, + GN2 stats.
__global__ __launch_bounds__(256) void k_point1(const float* __restrict__ feat,
                                                const float* __restrict__ W,
                                                const float* __restrict__ bias,
                                                const float* __restrict__ coefP,
                                                float* __restrict__ h1out,
                                                float* __restrict__ statsOut)
{
    __shared__ float w_lds[64 * 65];
    __shared__ float sred[256];
    const int b = blockIdx.x >> 9;
    const int n0 = (blockIdx.x & 511) * 64;
    const int wid = threadIdx.x >> 6, lane = threadIdx.x & 63;
    for (int k = threadIdx.x; k < 4096; k += 256)
        w_lds[(k & 63) * 65 + (k >> 6)] = W[k];   // w_lds[i][o] = W[o][i]
    __syncthreads();
    float wreg[64];
#pragma unroll
    for (int i = 0; i < 64; ++i) wreg[i] = w_lds[i * 65 + lane];
    const float bo = bias[lane];
    const float a = coefP[(b * 64 + lane) * 2], bb = coefP[(b * 64 + lane) * 2 + 1];
    float s = 0.f, s2 = 0.f;
    for (int j = 0; j < 16; ++j) {
        const int base = b * NB + n0 + wid * 16 + j;
        const float f = feat[base * 64 + lane];
        const float act = lrelu(a * f + bb);
        float o = bo;
#pragma unroll
        for (int i = 0; i < 64; ++i) o += rl(act, i) * wreg[i];
        h1out[base * 64 + lane] = o;
        s += o; s2 += o * o;
    }
    sred[threadIdx.x] = s; __syncthreads();
    if (threadIdx.x < 64) {
        float t = sred[threadIdx.x] + sred[threadIdx.x + 64] + sred[threadIdx.x + 128] + sred[threadIdx.x + 192];
        atomicAdd(&statsOut[(b * 64 + threadIdx.x) * 2], t);
    }
    __syncthreads();
    sred[threadIdx.x] = s2; __syncthreads();
    if (threadIdx.x < 64) {
        float t = sred[threadIdx.x] + sred[threadIdx.x + 64] + sred[threadIdx.x + 128] + sred[threadIdx.x + 192];
        atomicAdd(&statsOut[(b * 64 + threadIdx.x) * 2 + 1], t);
    }
}

// Final fused: point conv1x1 #2 + point residual + trilinear devox gather + output mix.
__global__ __launch_bounds__(256) void k_final(const float* __restrict__ pts,
                                               const float* __restrict__ feat,
                                               const float* __restrict__ h1,
                                               const float* __restrict__ W2,
                                               const float* __restrict__ bias2,
                                               const float* __restrict__ coefP1,
                                               const float* __restrict__ coefP2,
                                               const float* __restrict__ outg,
                                               float* __restrict__ out)
{
    __shared__ float w_lds[64 * 65];
    const int b = blockIdx.x >> 9;
    const int n0 = (blockIdx.x & 511) * 64;
    const int wid = threadIdx.x >> 6, lane = threadIdx.x & 63;
    for (int k = threadIdx.x; k < 4096; k += 256)
        w_lds[(k & 63) * 65 + (k >> 6)] = W2[k];
    __syncthreads();
    float wreg[64];
#pragma unroll
    for (int i = 0; i < 64; ++i) wreg[i] = w_lds[i * 65 + lane];
    const float bo = bias2[lane];
    const float a1 = coefP1[(b * 64 + lane) * 2], b1 = coefP1[(b * 64 + lane) * 2 + 1];
    const float a2 = coefP2[(b * 64 + lane) * 2], b2 = coefP2[(b * 64 + lane) * 2 + 1];
    for (int j = 0; j < 16; ++j) {
        const int base = b * NB + n0 + wid * 16 + j;
        const float f = feat[base * 64 + lane];
        const float fn = a1 * f + b1;
        const float act = lrelu(a2 * h1[base * 64 + lane] + b2);
        float o = bo;
#pragma unroll
        for (int i = 0; i < 64; ++i) o += rl(act, i) * wreg[i];
        const float ptsv = (o + fn) * INV_SQRT2;
        const float px = pts[base * 3 + 0], py = pts[base * 3 + 1], pz = pts[base * 3 + 2];
        int c0x, c0y, c0z, c1x, c1y, c1z; float fx, fy, fz;
        corner_setup(px, py, pz, c0x, c0y, c0z, c1x, c1y, c1z, fx, fy, fz);
        const float w0x = 1.f - fx, w0y = 1.f - fy, w0z = 1.f - fz;
        float dv = 0.f;
#pragma unroll
        for (int k = 0; k < 8; ++k) {
            const int cx = (k & 4) ? c1x : c0x;
            const int cy = (k & 2) ? c1y : c0y;
            const int cz = (k & 1) ? c1z : c0z;
            const float w = ((k & 4) ? fx : w0x) * ((k & 2) ? fy : w0y) * ((k & 1) ? fz : w0z);
            dv += w * outg[(b * VV + (cx * RR + cy) * RR + cz) * 64 + lane];
        }
        out[base * 64 + lane] = (ptsv + dv) * INV_SQRT2;
    }
}

extern "C" void kernel_launch(void* const* d_in, const int* in_sizes, int n_in,
                              void* d_out, int out_size, void* d_ws, size_t ws_size,
                              hipStream_t stream)
{
    const float* points   = (const float*)d_in[0];
    const float* features = (const float*)d_in[1];
    const float* conv1_w  = (const float*)d_in[2];
    const float* conv1_b  = (const float*)d_in[3];
    const float* conv2_w  = (const float*)d_in[4];
    const float* conv2_b  = (const float*)d_in[5];
    const float* g1_gamma = (const float*)d_in[6];
    const float* g1_beta  = (const float*)d_in[7];
    const float* g2_gamma = (const float*)d_in[8];
    const float* g2_beta  = (const float*)d_in[9];
    const float* p1w  = (const float*)d_in[10];
    const float* p1b  = (const float*)d_in[11];
    const float* p2w  = (const float*)d_in[12];
    const float* p2b  = (const float*)d_in[13];
    const float* pg1g = (const float*)d_in[14];
    const float* pg1b = (const float*)d_in[15];
    const float* pg2g = (const float*)d_in[16];
    const float* pg2b = (const float*)d_in[17];
    float* out = (float*)d_out;

    float* ws = (float*)d_ws;
    float* gridbuf  = ws;                       // 16777216 f: grid -> out_grid (in place)
    float* conv1o   = gridbuf + 16777216;       // 16777216 f (sort scratch aliased inside)
    float* h1       = conv1o + 16777216;        // 16777216 f
    unsigned short* wrb = (unsigned short*)(h1 + 16777216);   // 221184 ushort = 110592 f
    float* stats_p1 = h1 + 16777216 + 110592;   // 1024 f each
    float* stats_v1 = stats_p1 + 1024;
    float* stats_v2 = stats_v1 + 1024;
    float* stats_p2 = stats_v2 + 1024;
    float* coef_p1  = stats_p2 + 1024;
    float* coef_v1  = coef_p1 + 1024;
    float* coef_v2  = coef_v1 + 1024;
    float* coef_p2  = coef_v2 + 1024;

    // counting-sort scratch aliased into conv1o (dead until conv1 runs)
    uint2*    pairs = (uint2*)conv1o;                         // 2097152 x 8B = 4194304 f
    unsigned* cnt   = (unsigned*)(conv1o + 4194304);          // 262144
    unsigned* start = cnt + 262144;                           // 262160 (padded)
    unsigned* cur   = start + 262160;                         // 262144
    unsigned* bsum  = cur + 262144;                           // 256
    unsigned* boff  = bsum + 256;                             // 256

    size_t needed = (size_t)(coef_p2 + 1024 - ws) * sizeof(float);
    if (ws_size < needed) return;

    hipMemsetAsync(cnt, 0, (size_t)262144 * 4, stream);
    hipMemsetAsync(stats_p1, 0, (size_t)4096 * 4, stream);    // all 4 stats sets contiguous

    const size_t conv_lds = 104448 + 24576 + 512 + 512;       // 130048 B

    k_reorder_w<<<864, 256, 0, stream>>>(conv1_w, conv2_w, wrb);
    k_count<<<4096, 256, 0, stream>>>(points, features, cnt, stats_p1);
    k_coef<<<1, 512, 0, stream>>>(stats_p1, pg1g, pg1b, coef_p1);
    k_scan1<<<256, 256, 0, stream>>>(cnt, start, bsum);
    k_scan2<<<1, 256, 0, stream>>>(bsum, boff);
    k_scan3<<<256, 256, 0, stream>>>(start, boff, cur);
    k_fill<<<1024, 256, 0, stream>>>(points, cur, pairs);
    k_gather<<<2048, 256, 0, stream>>>(pairs, start, features, gridbuf, stats_v1);
    k_coef<<<1, 512, 0, stream>>>(stats_v1, g1_gamma, g1_beta, coef_v1);
    k_conv_mfma<<<1024, 512, conv_lds, stream>>>(gridbuf, wrb, conv1_b, coef_v1,
                                                 conv1o, stats_v2, nullptr, nullptr);
    k_coef<<<1, 512, 0, stream>>>(stats_v2, g2_gamma, g2_beta, coef_v2);
    k_conv_mfma<<<1024, 512, conv_lds, stream>>>(conv1o, wrb + 110592, conv2_b, coef_v2,
                                                 gridbuf, nullptr, gridbuf, coef_v1);
    k_point1<<<4096, 256, 0, stream>>>(features, p1w, p1b, coef_p1, h1, stats_p2);
    k_coef<<<1, 512, 0, stream>>>(stats_p2, pg2g, pg2b, coef_p2);
    k_final<<<4096, 256, 0, stream>>>(points, features, h1, p2w, p2b, coef_p1, coef_p2, gridbuf, out);
}

// Round 4
// 729.404 us; speedup vs baseline: 5.3723x; 1.1289x over previous
//
#include <hip/hip_runtime.h>

// Problem constants
#define BB 8
#define NB 32768
#define RR 32
#define VV (32*32*32)
#define TOTAL_PAIRS (BB*NB*8)          // 2097152
#define INV_SQRT2 0.70710678118654752440f

typedef __attribute__((ext_vector_type(8))) short s8v;      // 8 bf16 (MFMA A/B frag)
typedef __attribute__((ext_vector_type(8))) unsigned short u16x8;
typedef __attribute__((ext_vector_type(4))) float f4v;      // MFMA C/D frag

static __device__ __forceinline__ float lrelu(float x) { return x > 0.f ? x : 0.01f * x; }
static __device__ __forceinline__ float rl(float v, int i) {
    return __uint_as_float((unsigned)__builtin_amdgcn_readlane(__float_as_uint(v), i));
}
static __device__ __forceinline__ unsigned short f2bf(float x) {
    unsigned u = __float_as_uint(x);
    u += 0x7fff + ((u >> 16) & 1);          // RNE
    return (unsigned short)(u >> 16);
}

static __device__ __forceinline__ void corner_setup(float px, float py, float pz,
    int& c0x, int& c0y, int& c0z, int& c1x, int& c1y, int& c1z,
    float& fx, float& fy, float& fz)
{
    float cx = fminf(fmaxf(px, 0.f), 1.f) * 31.f;
    float cy = fminf(fmaxf(py, 0.f), 1.f) * 31.f;
    float cz = fminf(fmaxf(pz, 0.f), 1.f) * 31.f;
    float f0x = floorf(cx), f0y = floorf(cy), f0z = floorf(cz);
    c0x = (int)f0x; c0y = (int)f0y; c0z = (int)f0z;
    fx = cx - f0x; fy = cy - f0y; fz = cz - f0z;
    c1x = min(c0x + 1, 31); c1y = min(c0y + 1, 31); c1z = min(c0z + 1, 31);
}

// Reorder conv weights [O][I][3][3][3] f32 -> bf16 [conv][tap9][col=o][k=dz*64+i],
// pre-XOR-swizzled within each 384B col-row so LDS staging is a linear copy and
// swizzled ds_read_b128 at MFMA time is bank-conflict-free.
__global__ __launch_bounds__(256) void k_reorder_w(const float* __restrict__ w1,
                                                   const float* __restrict__ w2,
                                                   unsigned short* __restrict__ wrb)
{
    int idx = blockIdx.x * 256 + threadIdx.x;
    if (idx >= 2 * 9 * 64 * 192) return;
    int conv = idx / 110592; int r = idx - conv * 110592;
    int tap = r / 12288; r -= tap * 12288;
    int col = r / 192; int k = r - col * 192;
    int dz = k >> 6, i = k & 63;
    int dx = tap / 3, dy = tap - dx * 3;
    const float* w = conv ? w2 : w1;
    float v = w[(col * 64 + i) * 27 + (dx * 9 + dy * 3 + dz)];
    int kd = k ^ ((col & 7) << 3);          // ushort-index form of byte ^ ((col&7)<<4)
    wrb[conv * 110592 + tap * 12288 + col * 192 + kd] = f2bf(v);
}

// Phase A: count (voxel,corner) pairs per voxel + point-branch GN1 stats.
// XCD-swizzled: batch = bid&7 so (under round-robin dispatch) XCD k only
// touches batch k's cnt region (128 KB, L2-resident).
__global__ __launch_bounds__(256) void k_count(const float* __restrict__ pts,
                                               const float* __restrict__ feat,
                                               unsigned* __restrict__ cnt,
                                               float* __restrict__ statsP)
{
    __shared__ float sred[256];
    const int b = blockIdx.x & 7;
    const int n0 = (blockIdx.x >> 3) * 64;
    const int wid = threadIdx.x >> 6, lane = threadIdx.x & 63;
    float s = 0.f, s2 = 0.f;
    for (int j = 0; j < 16; ++j) {
        const int base = b * NB + n0 + wid * 16 + j;
        const float f = feat[base * 64 + lane];
        s += f; s2 += f * f;
        const float px = pts[base * 3 + 0], py = pts[base * 3 + 1], pz = pts[base * 3 + 2];
        int c0x, c0y, c0z, c1x, c1y, c1z; float fx, fy, fz;
        corner_setup(px, py, pz, c0x, c0y, c0z, c1x, c1y, c1z, fx, fy, fz);
        if (lane < 8) {
            const int cx = (lane & 4) ? c1x : c0x;
            const int cy = (lane & 2) ? c1y : c0y;
            const int cz = (lane & 1) ? c1z : c0z;
            atomicAdd(&cnt[b * VV + (cx * RR + cy) * RR + cz], 1u);
        }
    }
    sred[threadIdx.x] = s; __syncthreads();
    if (threadIdx.x < 64) {
        float t = sred[threadIdx.x] + sred[threadIdx.x + 64] + sred[threadIdx.x + 128] + sred[threadIdx.x + 192];
        atomicAdd(&statsP[(b * 64 + threadIdx.x) * 2], t);
    }
    __syncthreads();
    sred[threadIdx.x] = s2; __syncthreads();
    if (threadIdx.x < 64) {
        float t = sred[threadIdx.x] + sred[threadIdx.x + 64] + sred[threadIdx.x + 128] + sred[threadIdx.x + 192];
        atomicAdd(&statsP[(b * 64 + threadIdx.x) * 2 + 1], t);
    }
}

// Scan step 1: per-block (1024 counts) exclusive scan; emit block totals.
__global__ __launch_bounds__(256) void k_scan1(const unsigned* __restrict__ cnt,
                                               unsigned* __restrict__ start,
                                               unsigned* __restrict__ bsum)
{
    __shared__ unsigned sd[256];
    const int t = threadIdx.x;
    const uint4 c = ((const uint4*)cnt)[blockIdx.x * 256 + t];
    unsigned tsum = c.x + c.y + c.z + c.w;
    sd[t] = tsum; __syncthreads();
    for (int off = 1; off < 256; off <<= 1) {
        unsigned x = (t >= off) ? sd[t - off] : 0u;
        __syncthreads();
        sd[t] += x;
        __syncthreads();
    }
    unsigned excl = (t == 0) ? 0u : sd[t - 1];
    uint4 o;
    o.x = excl; o.y = excl + c.x; o.z = o.y + c.y; o.w = o.z + c.z;
    ((uint4*)start)[blockIdx.x * 256 + t] = o;
    if (t == 255) bsum[blockIdx.x] = sd[255];
}

// Scan step 2: exclusive scan of 256 block sums.
__global__ void k_scan2(const unsigned* __restrict__ bsum, unsigned* __restrict__ boff)
{
    __shared__ unsigned sd[256];
    const int t = threadIdx.x;
    sd[t] = bsum[t]; __syncthreads();
    for (int off = 1; off < 256; off <<= 1) {
        unsigned x = (t >= off) ? sd[t - off] : 0u;
        __syncthreads();
        sd[t] += x;
        __syncthreads();
    }
    boff[t] = (t == 0) ? 0u : sd[t - 1];
}

// Scan step 3: add block offsets; also produce the working cursor copy.
__global__ __launch_bounds__(256) void k_scan3(unsigned* __restrict__ start,
                                               const unsigned* __restrict__ boff,
                                               unsigned* __restrict__ cur)
{
    const int g = blockIdx.x * 256 + threadIdx.x;
    const unsigned o = boff[blockIdx.x];
    uint4 v = ((uint4*)start)[g];
    v.x += o; v.y += o; v.z += o; v.w += o;
    ((uint4*)start)[g] = v;
    ((uint4*)cur)[g] = v;
}

// Phase C: write (point, weight) pairs into per-voxel segments.
// XCD-swizzled: batch = bid&7 -> XCD k writes only batch k's ~2.1MB pair
// segment + 128KB cur (both L2-resident) -> pair lines fill in L2 before
// eviction, killing the 8x scattered-write amplification.
__global__ __launch_bounds__(256) void k_fill(const float* __restrict__ pts,
                                              unsigned* __restrict__ cur,
                                              uint2* __restrict__ pairs)
{
    const int b = blockIdx.x & 7;
    const int p = b * NB + (blockIdx.x >> 3) * 256 + threadIdx.x;
    const float px = pts[p * 3 + 0], py = pts[p * 3 + 1], pz = pts[p * 3 + 2];
    int c0x, c0y, c0z, c1x, c1y, c1z; float fx, fy, fz;
    corner_setup(px, py, pz, c0x, c0y, c0z, c1x, c1y, c1z, fx, fy, fz);
    const float w0x = 1.f - fx, w0y = 1.f - fy, w0z = 1.f - fz;
    const int bvv = b * VV;
#pragma unroll
    for (int k = 0; k < 8; ++k) {
        const int cx = (k & 4) ? c1x : c0x;
        const int cy = (k & 2) ? c1y : c0y;
        const int cz = (k & 1) ? c1z : c0z;
        const float w = ((k & 4) ? fx : w0x) * ((k & 2) ? fy : w0y) * ((k & 1) ? fz : w0z);
        unsigned slot = atomicAdd(&cur[bvv + (cx * RR + cy) * RR + cz], 1u);
        pairs[slot] = make_uint2((unsigned)p, __float_as_uint(w));
    }
}

// Phase D: per-voxel gather + normalize + voxel GN1 stats.
// XCD-swizzled: XCD k reads batch k's pairs segment + feature rows (8MB).
__global__ __launch_bounds__(256) void k_gather(const uint2* __restrict__ pairs,
                                                const unsigned* __restrict__ start,
                                                const float* __restrict__ feat,
                                                float* __restrict__ grid,
                                                float* __restrict__ statsV)
{
    __shared__ float sred[256];
    const int tid = threadIdx.x, wid = tid >> 6, lane = tid & 63;
    const int b = blockIdx.x & 7;
    const int vbase = b * VV + (blockIdx.x >> 3) * 128 + wid * 32;
    float s = 0.f, s2 = 0.f;
    for (int i = 0; i < 32; ++i) {
        const int v = vbase + i;
        const int p0 = start[v];
        const int p1 = (v == BB * VV - 1) ? TOTAL_PAIRS : (int)start[v + 1];
        float acc = 0.f, wsum = 0.f;
        for (int base = p0; base < p1; base += 64) {
            uint2 pr = make_uint2(0u, 0u);
            if (base + lane < p1) pr = pairs[base + lane];
            const int m = min(64, p1 - base);
            int j = 0;
            for (; j + 3 < m; j += 4) {
                unsigned u0 = (unsigned)__builtin_amdgcn_readlane((int)pr.x, j);
                unsigned u1 = (unsigned)__builtin_amdgcn_readlane((int)pr.x, j + 1);
                unsigned u2 = (unsigned)__builtin_amdgcn_readlane((int)pr.x, j + 2);
                unsigned u3 = (unsigned)__builtin_amdgcn_readlane((int)pr.x, j + 3);
                float w0 = __uint_as_float((unsigned)__builtin_amdgcn_readlane((int)pr.y, j));
                float w1 = __uint_as_float((unsigned)__builtin_amdgcn_readlane((int)pr.y, j + 1));
                float w2 = __uint_as_float((unsigned)__builtin_amdgcn_readlane((int)pr.y, j + 2));
                float w3 = __uint_as_float((unsigned)__builtin_amdgcn_readlane((int)pr.y, j + 3));
                float f0 = feat[(size_t)u0 * 64 + lane];
                float f1 = feat[(size_t)u1 * 64 + lane];
                float f2 = feat[(size_t)u2 * 64 + lane];
                float f3 = feat[(size_t)u3 * 64 + lane];
                acc = fmaf(w0, f0, acc); acc = fmaf(w1, f1, acc);
                acc = fmaf(w2, f2, acc); acc = fmaf(w3, f3, acc);
                wsum += w0 + w1 + w2 + w3;
            }
            for (; j < m; ++j) {
                unsigned u0 = (unsigned)__builtin_amdgcn_readlane((int)pr.x, j);
                float w0 = __uint_as_float((unsigned)__builtin_amdgcn_readlane((int)pr.y, j));
                acc = fmaf(w0, feat[(size_t)u0 * 64 + lane], acc);
                wsum += w0;
            }
        }
        const float val = acc / fmaxf(wsum, 1e-8f);
        grid[(size_t)v * 64 + lane] = val;
        s += val; s2 += val * val;
    }
    sred[tid] = s; __syncthreads();
    if (tid < 64) {
        float t = sred[tid] + sred[tid + 64] + sred[tid + 128] + sred[tid + 192];
        atomicAdd(&statsV[(b * 64 + tid) * 2], t);
    }
    __syncthreads();
    sred[tid] = s2; __syncthreads();
    if (tid < 64) {
        float t = sred[tid] + sred[tid + 64] + sred[tid + 128] + sred[tid + 192];
        atomicAdd(&statsV[(b * 64 + tid) * 2 + 1], t);
    }
}

// stats -> per-channel affine (a,b): y = a*x + b implements groupnorm (groups of 2 ch x 32768).
__global__ void k_coef(const float* __restrict__ stats, const float* __restrict__ gamma,
                       const float* __restrict__ beta, float* __restrict__ coef)
{
    int tid = threadIdx.x;           // 512 threads: b=tid>>6, c=tid&63
    int b = tid >> 6, c = tid & 63, g = c >> 1;
    float s = stats[(b * 64 + 2 * g) * 2] + stats[(b * 64 + 2 * g + 1) * 2];
    float q = stats[(b * 64 + 2 * g) * 2 + 1] + stats[(b * 64 + 2 * g + 1) * 2 + 1];
    float mean = s / 65536.f;
    float var = q / 65536.f - mean * mean;
    float a = gamma[c] * rsqrtf(var + 1e-5f);
    coef[(b * 64 + c) * 2] = a;
    coef[(b * 64 + c) * 2 + 1] = beta[c] - mean * a;
}

// 3x3x3 conv C=64->64 SAME as bf16 implicit GEMM on MFMA.
__global__ __launch_bounds__(512) void k_conv_mfma(const float* __restrict__ in,
                                                   const unsigned short* __restrict__ wrb,
                                                   const float* __restrict__ bias,
                                                   const float* __restrict__ coef_in,
                                                   float* out,
                                                   float* __restrict__ statsOut,
                                                   const float* resid,
                                                   const float* __restrict__ coef_res)
{
    extern __shared__ char smem[];
    unsigned short* in_lds = (unsigned short*)smem;                 // 52224 ushort = 104448 B
    unsigned short* w_lds  = (unsigned short*)(smem + 104448);      // 12288 ushort = 24576 B
    float* ca    = (float*)(smem + 129024);                         // 64
    float* cb    = ca + 64;                                         // 64
    float* sstat = cb + 64;                                         // 128

    const int b = blockIdx.x & 7;
    const int tile = blockIdx.x >> 3;
    const int x0 = (tile >> 3) * 2, y0 = (tile & 7) * 4;
    const int tid = threadIdx.x;

    if (tid < 64) {
        ca[tid] = coef_in[(b * 64 + tid) * 2];
        cb[tid] = coef_in[(b * 64 + tid) * 2 + 1];
    }
    if (tid < 128) sstat[tid] = 0.f;
    __syncthreads();

    // ---- stage input halo (affine+lrelu+cvt fused), swizzled ds_write_b128 ----
    for (int g = tid; g < 6528; g += 512) {           // 816 rows x 8 granules
        int row = g >> 3, s = g & 7;
        int px = row / 204;                            // 6*34
        int rem = row - px * 204;
        int py = rem / 34;
        int pz = rem - py * 34;
        int gx = x0 + px - 1, gy = y0 + py - 1, gz = pz - 1;
        int byteoff = row * 128 + ((s * 16) ^ ((pz & 7) << 4));
        u16x8* dst = (u16x8*)((char*)in_lds + byteoff);
        u16x8 o;
        if ((unsigned)gx < 32u && (unsigned)gy < 32u && (unsigned)gz < 32u) {
            const float* src = &in[(b * VV + (gx * RR + gy) * RR + gz) * 64 + s * 8];
            float4 v0 = *(const float4*)src;
            float4 v1 = *(const float4*)(src + 4);
            float xs[8] = {v0.x, v0.y, v0.z, v0.w, v1.x, v1.y, v1.z, v1.w};
            int ci = s * 8;
#pragma unroll
            for (int q = 0; q < 8; ++q) {
                float t = fmaf(ca[ci + q], xs[q], cb[ci + q]);
                o[q] = f2bf(lrelu(t));
            }
        } else {
            o = (u16x8)0;
        }
        *dst = o;
    }

    const int w = tid >> 6, l = tid & 63;
    const int l15 = l & 15, lq = l >> 4;
    const int xi = w >> 2, yi = w & 3;
    const int bxor = (l & 7) << 4;

    f4v acc[2][4];
#pragma unroll
    for (int nt = 0; nt < 4; ++nt) {
        float bv = bias[nt * 16 + l15];
        f4v bf = {bv, bv, bv, bv};
        acc[0][nt] = bf; acc[1][nt] = bf;
    }

    for (int tap = 0; tap < 9; ++tap) {
        __syncthreads();
        {   // stage this tap's weights: linear 48B/thread copy (pre-swizzled global)
            const unsigned short* src = wrb + tap * 12288 + tid * 24;
            u16x8* d = (u16x8*)(w_lds + tid * 24);
            u16x8 a0 = *(const u16x8*)src;
            u16x8 a1 = *(const u16x8*)(src + 8);
            u16x8 a2 = *(const u16x8*)(src + 16);
            d[0] = a0; d[1] = a1; d[2] = a2;
        }
        __syncthreads();
        const int dx = tap / 3, dy = tap - dx * 3;
        const int rowbase = ((xi + dx) * 6 + (yi + dy)) * 34;
#pragma unroll
        for (int ks = 0; ks < 6; ++ks) {
            const int dz = ks >> 1, cib = (ks & 1) * 32;
            s8v a0, a1;
            {
                int pz = l15 + dz;
                int boff = (rowbase + pz) * 128 + (((cib + lq * 8) * 2) ^ ((pz & 7) << 4));
                a0 = *(const s8v*)((const char*)in_lds + boff);
            }
            {
                int pz = 16 + l15 + dz;
                int boff = (rowbase + pz) * 128 + (((cib + lq * 8) * 2) ^ ((pz & 7) << 4));
                a1 = *(const s8v*)((const char*)in_lds + boff);
            }
#pragma unroll
            for (int nt = 0; nt < 4; ++nt) {
                int boff = (nt * 16 + l15) * 384 + ((ks * 64 + lq * 16) ^ bxor);
                s8v bf = *(const s8v*)((const char*)w_lds + boff);
                acc[0][nt] = __builtin_amdgcn_mfma_f32_16x16x32_bf16(a0, bf, acc[0][nt], 0, 0, 0);
                acc[1][nt] = __builtin_amdgcn_mfma_f32_16x16x32_bf16(a1, bf, acc[1][nt], 0, 0, 0);
            }
        }
    }

    // ---- epilogue ----
    const int outb = (b * VV + ((x0 + xi) * RR + (y0 + yi)) * RR) * 64;
    if (!resid) {
        // conv1: store raw output + GN2 stats
        float sa[4] = {0, 0, 0, 0}, sq[4] = {0, 0, 0, 0};
#pragma unroll
        for (int m = 0; m < 2; ++m)
#pragma unroll
            for (int nt = 0; nt < 4; ++nt)
#pragma unroll
                for (int j = 0; j < 4; ++j) {
                    int z = m * 16 + lq * 4 + j;
                    float v = acc[m][nt][j];
                    out[outb + z * 64 + nt * 16 + l15] = v;
                    sa[nt] += v; sq[nt] += v * v;
                }
#pragma unroll
        for (int nt = 0; nt < 4; ++nt) {
            float a = sa[nt], q = sq[nt];
            a += __shfl_xor(a, 16); q += __shfl_xor(q, 16);
            a += __shfl_xor(a, 32); q += __shfl_xor(q, 32);
            if (lq == 0) {
                atomicAdd(&sstat[(nt * 16 + l15) * 2], a);
                atomicAdd(&sstat[(nt * 16 + l15) * 2 + 1], q);
            }
        }
        __syncthreads();
        if (tid < 128) atomicAdd(&statsOut[b * 128 + tid], sstat[tid]);
    } else {
        // conv2: out = (conv + affine(resid)) / sqrt2, in place over resid
#pragma unroll
        for (int nt = 0; nt < 4; ++nt) {
            int ch = nt * 16 + l15;
            float a2 = coef_res[(b * 64 + ch) * 2];
            float b2 = coef_res[(b * 64 + ch) * 2 + 1];
#pragma unroll
            for (int m = 0; m < 2; ++m)
#pragma unroll
                for (int j = 0; j < 4; ++j) {
                    int z = m * 16 + lq * 4 + j;
                    int idx = outb + z * 64 + ch;
                    float r = resid[idx];
                    out[idx] = (acc[m][nt][j] + fmaf(a2, r, b2)) * INV_SQRT2;
                }
        }
    }
}

// Point branch conv1x1 #1: h = W @ lrelu(gn1(f)) + bias, + GN2 stats.
__global__ __launch_bounds__(256) void k_point1(const float* __restrict__ feat,
                                                const float* __restrict__ W,
                                                const float* __restrict__ bias,
                                                const float* __restrict__ coefP,
                                                float* __restrict__ h1out,
                                                float* __restrict__ statsOut)
{
    __shared__ float w_lds[64 * 65];
    __shared__ float sred[256];
    const int b = blockIdx.x >> 9;
    const int n0 = (blockIdx.x & 511) * 64;
    const int wid = threadIdx.x >> 6, lane = threadIdx.x & 63;
    for (int k = threadIdx.x; k < 4096; k += 256)
        w_lds[(k & 63) * 65 + (k >> 6)] = W[k];   // w_lds[i][o] = W[o][i]
    __syncthreads();
    float wreg[64];
#pragma unroll
    for (int i = 0; i < 64; ++i) wreg[i] = w_lds[i * 65 + lane];
    const float bo = bias[lane];
    const float a = coefP[(b * 64 + lane) * 2], bb = coefP[(b * 64 + lane) * 2 + 1];
    float s = 0.f, s2 = 0.f;
    for (int j = 0; j < 16; ++j) {
        const int base = b * NB + n0 + wid * 16 + j;
        const float f = feat[base * 64 + lane];
        const float act = lrelu(a * f + bb);
        float o = bo;
#pragma unroll
        for (int i = 0; i < 64; ++i) o += rl(act, i) * wreg[i];
        h1out[base * 64 + lane] = o;
        s += o; s2 += o * o;
    }
    sred[threadIdx.x] = s; __syncthreads();
    if (threadIdx.x < 64) {
        float t = sred[threadIdx.x] + sred[threadIdx.x + 64] + sred[threadIdx.x + 128] + sred[threadIdx.x + 192];
        atomicAdd(&statsOut[(b * 64 + threadIdx.x) * 2], t);
    }
    __syncthreads();
    sred[threadIdx.x] = s2; __syncthreads();
    if (threadIdx.x < 64) {
        float t = sred[threadIdx.x] + sred[threadIdx.x + 64] + sred[threadIdx.x + 128] + sred[threadIdx.x + 192];
        atomicAdd(&statsOut[(b * 64 + threadIdx.x) * 2 + 1], t);
    }
}

// Final fused: point conv1x1 #2 + point residual + trilinear devox gather + output mix.
// XCD-swizzled so each XCD's devox reads hit one batch's out_grid region.
__global__ __launch_bounds__(256) void k_final(const float* __restrict__ pts,
                                               const float* __restrict__ feat,
                                               const float* __restrict__ h1,
                                               const float* __restrict__ W2,
                                               const float* __restrict__ bias2,
                                               const float* __restrict__ coefP1,
                                               const float* __restrict__ coefP2,
                                               const float* __restrict__ outg,
                                               float* __restrict__ out)
{
    __shared__ float w_lds[64 * 65];
    const int b = blockIdx.x & 7;
    const int n0 = (blockIdx.x >> 3) * 64;
    const int wid = threadIdx.x >> 6, lane = threadIdx.x & 63;
    for (int k = threadIdx.x; k < 4096; k += 256)
        w_lds[(k & 63) * 65 + (k >> 6)] = W2[k];
    __syncthreads();
    float wreg[64];
#pragma unroll
    for (int i = 0; i < 64; ++i) wreg[i] = w_lds[i * 65 + lane];
    const float bo = bias2[lane];
    const float a1 = coefP1[(b * 64 + lane) * 2], b1 = coefP1[(b * 64 + lane) * 2 + 1];
    const float a2 = coefP2[(b * 64 + lane) * 2], b2 = coefP2[(b * 64 + lane) * 2 + 1];
    for (int j = 0; j < 16; ++j) {
        const int base = b * NB + n0 + wid * 16 + j;
        const float f = feat[base * 64 + lane];
        const float fn = a1 * f + b1;
        const float act = lrelu(a2 * h1[base * 64 + lane] + b2);
        float o = bo;
#pragma unroll
        for (int i = 0; i < 64; ++i) o += rl(act, i) * wreg[i];
        const float ptsv = (o + fn) * INV_SQRT2;
        const float px = pts[base * 3 + 0], py = pts[base * 3 + 1], pz = pts[base * 3 + 2];
        int c0x, c0y, c0z, c1x, c1y, c1z; float fx, fy, fz;
        corner_setup(px, py, pz, c0x, c0y, c0z, c1x, c1y, c1z, fx, fy, fz);
        const float w0x = 1.f - fx, w0y = 1.f - fy, w0z = 1.f - fz;
        float dv = 0.f;
#pragma unroll
        for (int k = 0; k < 8; ++k) {
            const int cx = (k & 4) ? c1x : c0x;
            const int cy = (k & 2) ? c1y : c0y;
            const int cz = (k & 1) ? c1z : c0z;
            const float w = ((k & 4) ? fx : w0x) * ((k & 2) ? fy : w0y) * ((k & 1) ? fz : w0z);
            dv += w * outg[(b * VV + (cx * RR + cy) * RR + cz) * 64 + lane];
        }
        out[base * 64 + lane] = (ptsv + dv) * INV_SQRT2;
    }
}

extern "C" void kernel_launch(void* const* d_in, const int* in_sizes, int n_in,
                              void* d_out, int out_size, void* d_ws, size_t ws_size,
                              hipStream_t stream)
{
    const float* points   = (const float*)d_in[0];
    const float* features = (const float*)d_in[1];
    const float* conv1_w  = (const float*)d_in[2];
    const float* conv1_b  = (const float*)d_in[3];
    const float* conv2_w  = (const float*)d_in[4];
    const float* conv2_b  = (const float*)d_in[5];
    const float* g1_gamma = (const float*)d_in[6];
    const float* g1_beta  = (const float*)d_in[7];
    const float* g2_gamma = (const float*)d_in[8];
    const float* g2_beta  = (const float*)d_in[9];
    const float* p1w  = (const float*)d_in[10];
    const float* p1b  = (const float*)d_in[11];
    const float* p2w  = (const float*)d_in[12];
    const float* p2b  = (const float*)d_in[13];
    const float* pg1g = (const float*)d_in[14];
    const float* pg1b = (const float*)d_in[15];
    const float* pg2g = (const float*)d_in[16];
    const float* pg2b = (const float*)d_in[17];
    float* out = (float*)d_out;

    float* ws = (float*)d_ws;
    float* gridbuf  = ws;                       // 16777216 f: grid -> out_grid (in place)
    float* conv1o   = gridbuf + 16777216;       // 16777216 f (sort scratch aliased inside)
    float* h1       = conv1o + 16777216;        // 16777216 f
    unsigned short* wrb = (unsigned short*)(h1 + 16777216);   // 221184 ushort = 110592 f
    float* stats_p1 = h1 + 16777216 + 110592;   // 1024 f each
    float* stats_v1 = stats_p1 + 1024;
    float* stats_v2 = stats_v1 + 1024;
    float* stats_p2 = stats_v2 + 1024;
    float* coef_p1  = stats_p2 + 1024;
    float* coef_v1  = coef_p1 + 1024;
    float* coef_v2  = coef_v1 + 1024;
    float* coef_p2  = coef_v2 + 1024;

    // counting-sort scratch aliased into conv1o (dead until conv1 runs)
    uint2*    pairs = (uint2*)conv1o;                         // 2097152 x 8B = 4194304 f
    unsigned* cnt   = (unsigned*)(conv1o + 4194304);          // 262144
    unsigned* start = cnt + 262144;                           // 262160 (padded)
    unsigned* cur   = start + 262160;                         // 262144
    unsigned* bsum  = cur + 262144;                           // 256
    unsigned* boff  = bsum + 256;                             // 256

    size_t needed = (size_t)(coef_p2 + 1024 - ws) * sizeof(float);
    if (ws_size < needed) return;

    hipMemsetAsync(cnt, 0, (size_t)262144 * 4, stream);
    hipMemsetAsync(stats_p1, 0, (size_t)4096 * 4, stream);    // all 4 stats sets contiguous

    const size_t conv_lds = 104448 + 24576 + 512 + 512;       // 130048 B

    k_reorder_w<<<864, 256, 0, stream>>>(conv1_w, conv2_w, wrb);
    k_count<<<4096, 256, 0, stream>>>(points, features, cnt, stats_p1);
    k_coef<<<1, 512, 0, stream>>>(stats_p1, pg1g, pg1b, coef_p1);
    k_scan1<<<256, 256, 0, stream>>>(cnt, start, bsum);
    k_scan2<<<1, 256, 0, stream>>>(bsum, boff);
    k_scan3<<<256, 256, 0, stream>>>(start, boff, cur);
    k_fill<<<1024, 256, 0, stream>>>(points, cur, pairs);
    k_gather<<<2048, 256, 0, stream>>>(pairs, start, features, gridbuf, stats_v1);
    k_coef<<<1, 512, 0, stream>>>(stats_v1, g1_gamma, g1_beta, coef_v1);
    k_conv_mfma<<<1024, 512, conv_lds, stream>>>(gridbuf, wrb, conv1_b, coef_v1,
                                                 conv1o, stats_v2, nullptr, nullptr);
    k_coef<<<1, 512, 0, stream>>>(stats_v2, g2_gamma, g2_beta, coef_v2);
    k_conv_mfma<<<1024, 512, conv_lds, stream>>>(conv1o, wrb + 110592, conv2_b, coef_v2,
                                                 gridbuf, nullptr, gridbuf, coef_v1);
    k_point1<<<4096, 256, 0, stream>>>(features, p1w, p1b, coef_p1, h1, stats_p2);
    k_coef<<<1, 512, 0, stream>>>(stats_p2, pg2g, pg2b, coef_p2);
    k_final<<<4096, 256, 0, stream>>>(points, features, h1, p2w, p2b, coef_p1, coef_p2, gridbuf, out);
}

// Round 5
// 572.466 us; speedup vs baseline: 6.8451x; 1.2741x over previous
//
#include <hip/hip_runtime.h>

// Problem constants
#define BB 8
#define NB 32768
#define RR 32
#define VV (32*32*32)
#define TOTAL_PAIRS (BB*NB*8)          // 2097152
#define INV_SQRT2 0.70710678118654752440f

typedef __attribute__((ext_vector_type(8))) short s8v;      // 8 bf16 (MFMA A/B frag)
typedef __attribute__((ext_vector_type(8))) unsigned short u16x8;
typedef __attribute__((ext_vector_type(4))) float f4v;      // MFMA C/D frag

static __device__ __forceinline__ float lrelu(float x) { return x > 0.f ? x : 0.01f * x; }
static __device__ __forceinline__ unsigned short f2bf(float x) {
    unsigned u = __float_as_uint(x);
    u += 0x7fff + ((u >> 16) & 1);          // RNE
    return (unsigned short)(u >> 16);
}
static __device__ __forceinline__ float bf2f(unsigned short u) {
    return __uint_as_float(((unsigned)u) << 16);
}

static __device__ __forceinline__ void corner_setup(float px, float py, float pz,
    int& c0x, int& c0y, int& c0z, int& c1x, int& c1y, int& c1z,
    float& fx, float& fy, float& fz)
{
    float cx = fminf(fmaxf(px, 0.f), 1.f) * 31.f;
    float cy = fminf(fmaxf(py, 0.f), 1.f) * 31.f;
    float cz = fminf(fmaxf(pz, 0.f), 1.f) * 31.f;
    float f0x = floorf(cx), f0y = floorf(cy), f0z = floorf(cz);
    c0x = (int)f0x; c0y = (int)f0y; c0z = (int)f0z;
    fx = cx - f0x; fy = cy - f0y; fz = cz - f0z;
    c1x = min(c0x + 1, 31); c1y = min(c0y + 1, 31); c1z = min(c0z + 1, 31);
}

// Reorder conv weights [O][I][3][3][3] f32 -> bf16 [conv][tap9][col=o][k=dz*64+i],
// pre-XOR-swizzled within each 384B col-row so LDS staging is a linear copy and
// swizzled ds_read_b128 at MFMA time is bank-conflict-free.
__global__ __launch_bounds__(256) void k_reorder_w(const float* __restrict__ w1,
                                                   const float* __restrict__ w2,
                                                   unsigned short* __restrict__ wrb)
{
    int idx = blockIdx.x * 256 + threadIdx.x;
    if (idx >= 2 * 9 * 64 * 192) return;
    int conv = idx / 110592; int r = idx - conv * 110592;
    int tap = r / 12288; r -= tap * 12288;
    int col = r / 192; int k = r - col * 192;
    int dz = k >> 6, i = k & 63;
    int dx = tap / 3, dy = tap - dx * 3;
    const float* w = conv ? w2 : w1;
    float v = w[(col * 64 + i) * 27 + (dx * 9 + dy * 3 + dz)];
    int kd = k ^ ((col & 7) << 3);          // ushort-index form of byte ^ ((col&7)<<4)
    wrb[conv * 110592 + tap * 12288 + col * 192 + kd] = f2bf(v);
}

// Phase A: count (voxel,corner) pairs per voxel + point-branch GN1 stats.
__global__ __launch_bounds__(256) void k_count(const float* __restrict__ pts,
                                               const float* __restrict__ feat,
                                               unsigned* __restrict__ cnt,
                                               float* __restrict__ statsP)
{
    __shared__ float sred[256];
    const int b = blockIdx.x & 7;
    const int n0 = (blockIdx.x >> 3) * 64;
    const int wid = threadIdx.x >> 6, lane = threadIdx.x & 63;
    float s = 0.f, s2 = 0.f;
    for (int j = 0; j < 16; ++j) {
        const int base = b * NB + n0 + wid * 16 + j;
        const float f = feat[base * 64 + lane];
        s += f; s2 += f * f;
        const float px = pts[base * 3 + 0], py = pts[base * 3 + 1], pz = pts[base * 3 + 2];
        int c0x, c0y, c0z, c1x, c1y, c1z; float fx, fy, fz;
        corner_setup(px, py, pz, c0x, c0y, c0z, c1x, c1y, c1z, fx, fy, fz);
        if (lane < 8) {
            const int cx = (lane & 4) ? c1x : c0x;
            const int cy = (lane & 2) ? c1y : c0y;
            const int cz = (lane & 1) ? c1z : c0z;
            atomicAdd(&cnt[b * VV + (cx * RR + cy) * RR + cz], 1u);
        }
    }
    sred[threadIdx.x] = s; __syncthreads();
    if (threadIdx.x < 64) {
        float t = sred[threadIdx.x] + sred[threadIdx.x + 64] + sred[threadIdx.x + 128] + sred[threadIdx.x + 192];
        atomicAdd(&statsP[(b * 64 + threadIdx.x) * 2], t);
    }
    __syncthreads();
    sred[threadIdx.x] = s2; __syncthreads();
    if (threadIdx.x < 64) {
        float t = sred[threadIdx.x] + sred[threadIdx.x + 64] + sred[threadIdx.x + 128] + sred[threadIdx.x + 192];
        atomicAdd(&statsP[(b * 64 + threadIdx.x) * 2 + 1], t);
    }
}

// Scan step 1: per-block (1024 counts) exclusive scan; emit block totals.
__global__ __launch_bounds__(256) void k_scan1(const unsigned* __restrict__ cnt,
                                               unsigned* __restrict__ start,
                                               unsigned* __restrict__ bsum)
{
    __shared__ unsigned sd[256];
    const int t = threadIdx.x;
    const uint4 c = ((const uint4*)cnt)[blockIdx.x * 256 + t];
    unsigned tsum = c.x + c.y + c.z + c.w;
    sd[t] = tsum; __syncthreads();
    for (int off = 1; off < 256; off <<= 1) {
        unsigned x = (t >= off) ? sd[t - off] : 0u;
        __syncthreads();
        sd[t] += x;
        __syncthreads();
    }
    unsigned excl = (t == 0) ? 0u : sd[t - 1];
    uint4 o;
    o.x = excl; o.y = excl + c.x; o.z = o.y + c.y; o.w = o.z + c.z;
    ((uint4*)start)[blockIdx.x * 256 + t] = o;
    if (t == 255) bsum[blockIdx.x] = sd[255];
}

// Scan step 2: exclusive scan of 256 block sums.
__global__ void k_scan2(const unsigned* __restrict__ bsum, unsigned* __restrict__ boff)
{
    __shared__ unsigned sd[256];
    const int t = threadIdx.x;
    sd[t] = bsum[t]; __syncthreads();
    for (int off = 1; off < 256; off <<= 1) {
        unsigned x = (t >= off) ? sd[t - off] : 0u;
        __syncthreads();
        sd[t] += x;
        __syncthreads();
    }
    boff[t] = (t == 0) ? 0u : sd[t - 1];
}

// Scan step 3: add block offsets; also produce the working cursor copy.
__global__ __launch_bounds__(256) void k_scan3(unsigned* __restrict__ start,
                                               const unsigned* __restrict__ boff,
                                               unsigned* __restrict__ cur)
{
    const int g = blockIdx.x * 256 + threadIdx.x;
    const unsigned o = boff[blockIdx.x];
    uint4 v = ((uint4*)start)[g];
    v.x += o; v.y += o; v.z += o; v.w += o;
    ((uint4*)start)[g] = v;
    ((uint4*)cur)[g] = v;
}

// Phase C: write (point, weight) pairs into per-voxel segments. XCD-swizzled.
__global__ __launch_bounds__(256) void k_fill(const float* __restrict__ pts,
                                              unsigned* __restrict__ cur,
                                              uint2* __restrict__ pairs)
{
    const int b = blockIdx.x & 7;
    const int p = b * NB + (blockIdx.x >> 3) * 256 + threadIdx.x;
    const float px = pts[p * 3 + 0], py = pts[p * 3 + 1], pz = pts[p * 3 + 2];
    int c0x, c0y, c0z, c1x, c1y, c1z; float fx, fy, fz;
    corner_setup(px, py, pz, c0x, c0y, c0z, c1x, c1y, c1z, fx, fy, fz);
    const float w0x = 1.f - fx, w0y = 1.f - fy, w0z = 1.f - fz;
    const int bvv = b * VV;
#pragma unroll
    for (int k = 0; k < 8; ++k) {
        const int cx = (k & 4) ? c1x : c0x;
        const int cy = (k & 2) ? c1y : c0y;
        const int cz = (k & 1) ? c1z : c0z;
        const float w = ((k & 4) ? fx : w0x) * ((k & 2) ? fy : w0y) * ((k & 1) ? fz : w0z);
        unsigned slot = atomicAdd(&cur[bvv + (cx * RR + cy) * RR + cz], 1u);
        pairs[slot] = make_uint2((unsigned)p, __float_as_uint(w));
    }
}

// Phase D: per-voxel gather + normalize + voxel GN1 stats. XCD-swizzled.
__global__ __launch_bounds__(256) void k_gather(const uint2* __restrict__ pairs,
                                                const unsigned* __restrict__ start,
                                                const float* __restrict__ feat,
                                                float* __restrict__ grid,
                                                float* __restrict__ statsV)
{
    __shared__ float sred[256];
    const int tid = threadIdx.x, wid = tid >> 6, lane = tid & 63;
    const int b = blockIdx.x & 7;
    const int vbase = b * VV + (blockIdx.x >> 3) * 128 + wid * 32;
    float s = 0.f, s2 = 0.f;
    for (int i = 0; i < 32; ++i) {
        const int v = vbase + i;
        const int p0 = start[v];
        const int p1 = (v == BB * VV - 1) ? TOTAL_PAIRS : (int)start[v + 1];
        float acc = 0.f, wsum = 0.f;
        for (int base = p0; base < p1; base += 64) {
            uint2 pr = make_uint2(0u, 0u);
            if (base + lane < p1) pr = pairs[base + lane];
            const int m = min(64, p1 - base);
            int j = 0;
            for (; j + 3 < m; j += 4) {
                unsigned u0 = (unsigned)__builtin_amdgcn_readlane((int)pr.x, j);
                unsigned u1 = (unsigned)__builtin_amdgcn_readlane((int)pr.x, j + 1);
                unsigned u2 = (unsigned)__builtin_amdgcn_readlane((int)pr.x, j + 2);
                unsigned u3 = (unsigned)__builtin_amdgcn_readlane((int)pr.x, j + 3);
                float w0 = __uint_as_float((unsigned)__builtin_amdgcn_readlane((int)pr.y, j));
                float w1 = __uint_as_float((unsigned)__builtin_amdgcn_readlane((int)pr.y, j + 1));
                float w2 = __uint_as_float((unsigned)__builtin_amdgcn_readlane((int)pr.y, j + 2));
                float w3 = __uint_as_float((unsigned)__builtin_amdgcn_readlane((int)pr.y, j + 3));
                float f0 = feat[(size_t)u0 * 64 + lane];
                float f1 = feat[(size_t)u1 * 64 + lane];
                float f2 = feat[(size_t)u2 * 64 + lane];
                float f3 = feat[(size_t)u3 * 64 + lane];
                acc = fmaf(w0, f0, acc); acc = fmaf(w1, f1, acc);
                acc = fmaf(w2, f2, acc); acc = fmaf(w3, f3, acc);
                wsum += w0 + w1 + w2 + w3;
            }
            for (; j < m; ++j) {
                unsigned u0 = (unsigned)__builtin_amdgcn_readlane((int)pr.x, j);
                float w0 = __uint_as_float((unsigned)__builtin_amdgcn_readlane((int)pr.y, j));
                acc = fmaf(w0, feat[(size_t)u0 * 64 + lane], acc);
                wsum += w0;
            }
        }
        const float val = acc / fmaxf(wsum, 1e-8f);
        grid[(size_t)v * 64 + lane] = val;
        s += val; s2 += val * val;
    }
    sred[tid] = s; __syncthreads();
    if (tid < 64) {
        float t = sred[tid] + sred[tid + 64] + sred[tid + 128] + sred[tid + 192];
        atomicAdd(&statsV[(b * 64 + tid) * 2], t);
    }
    __syncthreads();
    sred[tid] = s2; __syncthreads();
    if (tid < 64) {
        float t = sred[tid] + sred[tid + 64] + sred[tid + 128] + sred[tid + 192];
        atomicAdd(&statsV[(b * 64 + tid) * 2 + 1], t);
    }
}

// stats -> per-channel affine (a,b): y = a*x + b implements groupnorm (groups of 2 ch x 32768).
__global__ void k_coef(const float* __restrict__ stats, const float* __restrict__ gamma,
                       const float* __restrict__ beta, float* __restrict__ coef)
{
    int tid = threadIdx.x;           // 512 threads: b=tid>>6, c=tid&63
    int b = tid >> 6, c = tid & 63, g = c >> 1;
    float s = stats[(b * 64 + 2 * g) * 2] + stats[(b * 64 + 2 * g + 1) * 2];
    float q = stats[(b * 64 + 2 * g) * 2 + 1] + stats[(b * 64 + 2 * g + 1) * 2 + 1];
    float mean = s / 65536.f;
    float var = q / 65536.f - mean * mean;
    float a = gamma[c] * rsqrtf(var + 1e-5f);
    coef[(b * 64 + c) * 2] = a;
    coef[(b * 64 + c) * 2 + 1] = beta[c] - mean * a;
}

// 3x3x3 conv C=64->64 SAME as bf16 implicit GEMM on MFMA.
__global__ __launch_bounds__(512) void k_conv_mfma(const float* __restrict__ in,
                                                   const unsigned short* __restrict__ wrb,
                                                   const float* __restrict__ bias,
                                                   const float* __restrict__ coef_in,
                                                   float* out,
                                                   float* __restrict__ statsOut,
                                                   const float* resid,
                                                   const float* __restrict__ coef_res)
{
    extern __shared__ char smem[];
    unsigned short* in_lds = (unsigned short*)smem;                 // 52224 ushort = 104448 B
    unsigned short* w_lds  = (unsigned short*)(smem + 104448);      // 12288 ushort = 24576 B
    float* ca    = (float*)(smem + 129024);                         // 64
    float* cb    = ca + 64;                                         // 64
    float* sstat = cb + 64;                                         // 128

    const int b = blockIdx.x & 7;
    const int tile = blockIdx.x >> 3;
    const int x0 = (tile >> 3) * 2, y0 = (tile & 7) * 4;
    const int tid = threadIdx.x;

    if (tid < 64) {
        ca[tid] = coef_in[(b * 64 + tid) * 2];
        cb[tid] = coef_in[(b * 64 + tid) * 2 + 1];
    }
    if (tid < 128) sstat[tid] = 0.f;
    __syncthreads();

    // ---- stage input halo (affine+lrelu+cvt fused), swizzled ds_write_b128 ----
    for (int g = tid; g < 6528; g += 512) {           // 816 rows x 8 granules
        int row = g >> 3, s = g & 7;
        int px = row / 204;                            // 6*34
        int rem = row - px * 204;
        int py = rem / 34;
        int pz = rem - py * 34;
        int gx = x0 + px - 1, gy = y0 + py - 1, gz = pz - 1;
        int byteoff = row * 128 + ((s * 16) ^ ((pz & 7) << 4));
        u16x8* dst = (u16x8*)((char*)in_lds + byteoff);
        u16x8 o;
        if ((unsigned)gx < 32u && (unsigned)gy < 32u && (unsigned)gz < 32u) {
            const float* src = &in[(b * VV + (gx * RR + gy) * RR + gz) * 64 + s * 8];
            float4 v0 = *(const float4*)src;
            float4 v1 = *(const float4*)(src + 4);
            float xs[8] = {v0.x, v0.y, v0.z, v0.w, v1.x, v1.y, v1.z, v1.w};
            int ci = s * 8;
#pragma unroll
            for (int q = 0; q < 8; ++q) {
                float t = fmaf(ca[ci + q], xs[q], cb[ci + q]);
                o[q] = f2bf(lrelu(t));
            }
        } else {
            o = (u16x8)0;
        }
        *dst = o;
    }

    const int w = tid >> 6, l = tid & 63;
    const int l15 = l & 15, lq = l >> 4;
    const int xi = w >> 2, yi = w & 3;
    const int bxor = (l & 7) << 4;

    f4v acc[2][4];
#pragma unroll
    for (int nt = 0; nt < 4; ++nt) {
        float bv = bias[nt * 16 + l15];
        f4v bf = {bv, bv, bv, bv};
        acc[0][nt] = bf; acc[1][nt] = bf;
    }

    for (int tap = 0; tap < 9; ++tap) {
        __syncthreads();
        {   // stage this tap's weights: linear 48B/thread copy (pre-swizzled global)
            const unsigned short* src = wrb + tap * 12288 + tid * 24;
            u16x8* d = (u16x8*)(w_lds + tid * 24);
            u16x8 a0 = *(const u16x8*)src;
            u16x8 a1 = *(const u16x8*)(src + 8);
            u16x8 a2 = *(const u16x8*)(src + 16);
            d[0] = a0; d[1] = a1; d[2] = a2;
        }
        __syncthreads();
        const int dx = tap / 3, dy = tap - dx * 3;
        const int rowbase = ((xi + dx) * 6 + (yi + dy)) * 34;
#pragma unroll
        for (int ks = 0; ks < 6; ++ks) {
            const int dz = ks >> 1, cib = (ks & 1) * 32;
            s8v a0, a1;
            {
                int pz = l15 + dz;
                int boff = (rowbase + pz) * 128 + (((cib + lq * 8) * 2) ^ ((pz & 7) << 4));
                a0 = *(const s8v*)((const char*)in_lds + boff);
            }
            {
                int pz = 16 + l15 + dz;
                int boff = (rowbase + pz) * 128 + (((cib + lq * 8) * 2) ^ ((pz & 7) << 4));
                a1 = *(const s8v*)((const char*)in_lds + boff);
            }
#pragma unroll
            for (int nt = 0; nt < 4; ++nt) {
                int boff = (nt * 16 + l15) * 384 + ((ks * 64 + lq * 16) ^ bxor);
                s8v bf = *(const s8v*)((const char*)w_lds + boff);
                acc[0][nt] = __builtin_amdgcn_mfma_f32_16x16x32_bf16(a0, bf, acc[0][nt], 0, 0, 0);
                acc[1][nt] = __builtin_amdgcn_mfma_f32_16x16x32_bf16(a1, bf, acc[1][nt], 0, 0, 0);
            }
        }
    }

    // ---- epilogue ----
    const int outb = (b * VV + ((x0 + xi) * RR + (y0 + yi)) * RR) * 64;
    if (!resid) {
        // conv1: store raw output + GN2 stats
        float sa[4] = {0, 0, 0, 0}, sq[4] = {0, 0, 0, 0};
#pragma unroll
        for (int m = 0; m < 2; ++m)
#pragma unroll
            for (int nt = 0; nt < 4; ++nt)
#pragma unroll
                for (int j = 0; j < 4; ++j) {
                    int z = m * 16 + lq * 4 + j;
                    float v = acc[m][nt][j];
                    out[outb + z * 64 + nt * 16 + l15] = v;
                    sa[nt] += v; sq[nt] += v * v;
                }
#pragma unroll
        for (int nt = 0; nt < 4; ++nt) {
            float a = sa[nt], q = sq[nt];
            a += __shfl_xor(a, 16); q += __shfl_xor(q, 16);
            a += __shfl_xor(a, 32); q += __shfl_xor(q, 32);
            if (lq == 0) {
                atomicAdd(&sstat[(nt * 16 + l15) * 2], a);
                atomicAdd(&sstat[(nt * 16 + l15) * 2 + 1], q);
            }
        }
        __syncthreads();
        if (tid < 128) atomicAdd(&statsOut[b * 128 + tid], sstat[tid]);
    } else {
        // conv2: out = (conv + affine(resid)) / sqrt2, in place over resid
#pragma unroll
        for (int nt = 0; nt < 4; ++nt) {
            int ch = nt * 16 + l15;
            float a2 = coef_res[(b * 64 + ch) * 2];
            float b2 = coef_res[(b * 64 + ch) * 2 + 1];
#pragma unroll
            for (int m = 0; m < 2; ++m)
#pragma unroll
                for (int j = 0; j < 4; ++j) {
                    int z = m * 16 + lq * 4 + j;
                    int idx = outb + z * 64 + ch;
                    float r = resid[idx];
                    out[idx] = (acc[m][nt][j] + fmaf(a2, r, b2)) * INV_SQRT2;
                }
        }
    }
}

// Point branch conv1x1 #1 on MFMA: h = W @ lrelu(gn1(f)) + bias; h stored bf16; GN2 stats.
// Block = 4 waves x 32 points = 128 points. A = activations [32x64], B = W^T [64col x 64k].
__global__ __launch_bounds__(256) void k_point1(const float* __restrict__ feat,
                                                const float* __restrict__ W,
                                                const float* __restrict__ bias,
                                                const float* __restrict__ coefP,
                                                unsigned short* __restrict__ h1out,
                                                float* __restrict__ statsOut)
{
    __shared__ unsigned short actA[4][2048];   // [wave][32 pts][64 ch] swizzled
    __shared__ unsigned short wW[4096];        // [col=o][k=i] swizzled
    __shared__ float ca[64], cb[64];
    __shared__ float sstat[128];
    const int b = blockIdx.x & 7;
    const int n0 = (blockIdx.x >> 3) * 128;
    const int tid = threadIdx.x, w = tid >> 6, l = tid & 63;
    const int l15 = l & 15, lq = l >> 4;

    if (tid < 64) {
        ca[tid] = coefP[(b * 64 + tid) * 2];
        cb[tid] = coefP[(b * 64 + tid) * 2 + 1];
    }
    if (tid < 128) sstat[tid] = 0.f;
    {   // stage W (bf16, row-XOR swizzled): thread -> 16 elems of row o
        int o = tid >> 2, i0 = (tid & 3) * 16, sw = (o & 7) << 3;
        const float* src = W + o * 64 + i0;
#pragma unroll
        for (int q = 0; q < 16; ++q) wW[o * 64 + ((i0 + q) ^ sw)] = f2bf(src[q]);
    }
    __syncthreads();

    // stage activations: lane covers half a point row (32 ch)
    const int p = l >> 1, half = l & 1;
    const int gp = b * NB + n0 + w * 32 + p;
    {
        const float* src = feat + (size_t)gp * 64 + half * 32;
        const int sw = (p & 7) << 3;
#pragma unroll
        for (int q2 = 0; q2 < 4; ++q2) {
            float4 v0 = *(const float4*)(src + q2 * 8);
            float4 v1 = *(const float4*)(src + q2 * 8 + 4);
            float xs[8] = {v0.x, v0.y, v0.z, v0.w, v1.x, v1.y, v1.z, v1.w};
            int ci = half * 32 + q2 * 8;
            u16x8 o_;
#pragma unroll
            for (int q = 0; q < 8; ++q)
                o_[q] = f2bf(lrelu(fmaf(ca[ci + q], xs[q], cb[ci + q])));
            *(u16x8*)&actA[w][p * 64 + (ci ^ sw)] = o_;
        }
    }
    __syncthreads();

    f4v acc[2][4];
#pragma unroll
    for (int nt = 0; nt < 4; ++nt) {
        float bv = bias[nt * 16 + l15];
        f4v bf = {bv, bv, bv, bv};
        acc[0][nt] = bf; acc[1][nt] = bf;
    }
    const unsigned short* aw = actA[w];
#pragma unroll
    for (int kk = 0; kk < 2; ++kk) {
        s8v a0, a1;
        { int r = l15;      a0 = *(const s8v*)&aw[r * 64 + ((kk * 32 + lq * 8) ^ ((r & 7) << 3))]; }
        { int r = 16 + l15; a1 = *(const s8v*)&aw[r * 64 + ((kk * 32 + lq * 8) ^ ((r & 7) << 3))]; }
#pragma unroll
        for (int nt = 0; nt < 4; ++nt) {
            int col = nt * 16 + l15;
            s8v bf = *(const s8v*)&wW[col * 64 + ((kk * 32 + lq * 8) ^ ((col & 7) << 3))];
            acc[0][nt] = __builtin_amdgcn_mfma_f32_16x16x32_bf16(a0, bf, acc[0][nt], 0, 0, 0);
            acc[1][nt] = __builtin_amdgcn_mfma_f32_16x16x32_bf16(a1, bf, acc[1][nt], 0, 0, 0);
        }
    }

    // stats (f32 accs) + bf16 h via LDS transpose
    float sa[4] = {0, 0, 0, 0}, sq[4] = {0, 0, 0, 0};
#pragma unroll
    for (int m = 0; m < 2; ++m)
#pragma unroll
        for (int nt = 0; nt < 4; ++nt)
#pragma unroll
            for (int j = 0; j < 4; ++j) {
                float v = acc[m][nt][j];
                sa[nt] += v; sq[nt] += v * v;
                actA[w][(m * 16 + lq * 4 + j) * 64 + nt * 16 + l15] = f2bf(v);
            }
#pragma unroll
    for (int nt = 0; nt < 4; ++nt) {
        float a = sa[nt], q = sq[nt];
        a += __shfl_xor(a, 16); q += __shfl_xor(q, 16);
        a += __shfl_xor(a, 32); q += __shfl_xor(q, 32);
        if (lq == 0) {
            atomicAdd(&sstat[(nt * 16 + l15) * 2], a);
            atomicAdd(&sstat[(nt * 16 + l15) * 2 + 1], q);
        }
    }
    {   // coalesced bf16 store (wave-local tile, no barrier needed)
        u16x8* dst = (u16x8*)(h1out + (size_t)gp * 64 + half * 32);
        const u16x8* srcl = (const u16x8*)&actA[w][p * 64 + half * 32];
        dst[0] = srcl[0]; dst[1] = srcl[1]; dst[2] = srcl[2]; dst[3] = srcl[3];
    }
    __syncthreads();
    if (tid < 128) atomicAdd(&statsOut[b * 128 + tid], sstat[tid]);
}

// Final fused on MFMA: point conv1x1 #2 (from bf16 h1) + point residual +
// trilinear devox gather + output mix. Phase 1: MFMA -> po LDS. Phase 2: per-point
// lane=channel layout for coalesced devox.
__global__ __launch_bounds__(256) void k_final(const float* __restrict__ pts,
                                               const float* __restrict__ feat,
                                               const unsigned short* __restrict__ h1,
                                               const float* __restrict__ W2,
                                               const float* __restrict__ bias2,
                                               const float* __restrict__ coefP1,
                                               const float* __restrict__ coefP2,
                                               const float* __restrict__ outg,
                                               float* __restrict__ out)
{
    __shared__ unsigned short actA[4][2048];
    __shared__ unsigned short wW[4096];
    __shared__ float ca1[64], cb1[64], ca2[64], cb2[64];
    __shared__ float po[128 * 65];
    const int b = blockIdx.x & 7;
    const int n0 = (blockIdx.x >> 3) * 128;
    const int tid = threadIdx.x, w = tid >> 6, l = tid & 63;
    const int l15 = l & 15, lq = l >> 4;

    if (tid < 64) {
        ca1[tid] = coefP1[(b * 64 + tid) * 2];
        cb1[tid] = coefP1[(b * 64 + tid) * 2 + 1];
        ca2[tid] = coefP2[(b * 64 + tid) * 2];
        cb2[tid] = coefP2[(b * 64 + tid) * 2 + 1];
    }
    {
        int o = tid >> 2, i0 = (tid & 3) * 16, sw = (o & 7) << 3;
        const float* src = W2 + o * 64 + i0;
#pragma unroll
        for (int q = 0; q < 16; ++q) wW[o * 64 + ((i0 + q) ^ sw)] = f2bf(src[q]);
    }
    __syncthreads();

    const int p = l >> 1, half = l & 1;
    const int gp = b * NB + n0 + w * 32 + p;
    {   // act = lrelu(a2 * h1 + b2), h1 is bf16
        const u16x8* src = (const u16x8*)(h1 + (size_t)gp * 64 + half * 32);
        const int sw = (p & 7) << 3;
#pragma unroll
        for (int q2 = 0; q2 < 4; ++q2) {
            u16x8 hv = src[q2];
            int ci = half * 32 + q2 * 8;
            u16x8 o_;
#pragma unroll
            for (int q = 0; q < 8; ++q)
                o_[q] = f2bf(lrelu(fmaf(ca2[ci + q], bf2f(hv[q]), cb2[ci + q])));
            *(u16x8*)&actA[w][p * 64 + (ci ^ sw)] = o_;
        }
    }
    __syncthreads();

    f4v acc[2][4];
#pragma unroll
    for (int nt = 0; nt < 4; ++nt) {
        float bv = bias2[nt * 16 + l15];
        f4v bf = {bv, bv, bv, bv};
        acc[0][nt] = bf; acc[1][nt] = bf;
    }
    const unsigned short* aw = actA[w];
#pragma unroll
    for (int kk = 0; kk < 2; ++kk) {
        s8v a0, a1;
        { int r = l15;      a0 = *(const s8v*)&aw[r * 64 + ((kk * 32 + lq * 8) ^ ((r & 7) << 3))]; }
        { int r = 16 + l15; a1 = *(const s8v*)&aw[r * 64 + ((kk * 32 + lq * 8) ^ ((r & 7) << 3))]; }
#pragma unroll
        for (int nt = 0; nt < 4; ++nt) {
            int col = nt * 16 + l15;
            s8v bf = *(const s8v*)&wW[col * 64 + ((kk * 32 + lq * 8) ^ ((col & 7) << 3))];
            acc[0][nt] = __builtin_amdgcn_mfma_f32_16x16x32_bf16(a0, bf, acc[0][nt], 0, 0, 0);
            acc[1][nt] = __builtin_amdgcn_mfma_f32_16x16x32_bf16(a1, bf, acc[1][nt], 0, 0, 0);
        }
    }
#pragma unroll
    for (int m = 0; m < 2; ++m)
#pragma unroll
        for (int nt = 0; nt < 4; ++nt)
#pragma unroll
            for (int j = 0; j < 4; ++j)
                po[(w * 32 + m * 16 + lq * 4 + j) * 65 + nt * 16 + l15] = acc[m][nt][j];
    __syncthreads();

    // Phase 2: per-point devox + residual + mix (lane = channel)
    for (int i = 0; i < 32; ++i) {
        const int pl = w * 32 + i;
        const int g2 = b * NB + n0 + pl;
        const float f = feat[(size_t)g2 * 64 + l];
        const float fn = fmaf(ca1[l], f, cb1[l]);
        const float o = po[pl * 65 + l];
        const float ptsv = (o + fn) * INV_SQRT2;
        const float px = pts[g2 * 3 + 0], py = pts[g2 * 3 + 1], pz = pts[g2 * 3 + 2];
        int c0x, c0y, c0z, c1x, c1y, c1z; float fx, fy, fz;
        corner_setup(px, py, pz, c0x, c0y, c0z, c1x, c1y, c1z, fx, fy, fz);
        const float w0x = 1.f - fx, w0y = 1.f - fy, w0z = 1.f - fz;
        float dv = 0.f;
#pragma unroll
        for (int k = 0; k < 8; ++k) {
            const int cx = (k & 4) ? c1x : c0x;
            const int cy = (k & 2) ? c1y : c0y;
            const int cz = (k & 1) ? c1z : c0z;
            const float wgt = ((k & 4) ? fx : w0x) * ((k & 2) ? fy : w0y) * ((k & 1) ? fz : w0z);
            dv = fmaf(wgt, outg[(b * VV + (cx * RR + cy) * RR + cz) * 64 + l], dv);
        }
        out[(size_t)g2 * 64 + l] = (ptsv + dv) * INV_SQRT2;
    }
}

extern "C" void kernel_launch(void* const* d_in, const int* in_sizes, int n_in,
                              void* d_out, int out_size, void* d_ws, size_t ws_size,
                              hipStream_t stream)
{
    const float* points   = (const float*)d_in[0];
    const float* features = (const float*)d_in[1];
    const float* conv1_w  = (const float*)d_in[2];
    const float* conv1_b  = (const float*)d_in[3];
    const float* conv2_w  = (const float*)d_in[4];
    const float* conv2_b  = (const float*)d_in[5];
    const float* g1_gamma = (const float*)d_in[6];
    const float* g1_beta  = (const float*)d_in[7];
    const float* g2_gamma = (const float*)d_in[8];
    const float* g2_beta  = (const float*)d_in[9];
    const float* p1w  = (const float*)d_in[10];
    const float* p1b  = (const float*)d_in[11];
    const float* p2w  = (const float*)d_in[12];
    const float* p2b  = (const float*)d_in[13];
    const float* pg1g = (const float*)d_in[14];
    const float* pg1b = (const float*)d_in[15];
    const float* pg2g = (const float*)d_in[16];
    const float* pg2b = (const float*)d_in[17];
    float* out = (float*)d_out;

    float* ws = (float*)d_ws;
    float* gridbuf  = ws;                       // 16777216 f: grid -> out_grid (in place)
    float* conv1o   = gridbuf + 16777216;       // 16777216 f (sort scratch aliased inside)
    float* h1f      = conv1o + 16777216;        // region reserved 16777216 f; h1 uses 4.2M f as bf16
    unsigned short* h1b = (unsigned short*)h1f;
    unsigned short* wrb = (unsigned short*)(h1f + 16777216);  // 221184 ushort = 110592 f
    float* stats_p1 = h1f + 16777216 + 110592;  // 1024 f each
    float* stats_v1 = stats_p1 + 1024;
    float* stats_v2 = stats_v1 + 1024;
    float* stats_p2 = stats_v2 + 1024;
    float* coef_p1  = stats_p2 + 1024;
    float* coef_v1  = coef_p1 + 1024;
    float* coef_v2  = coef_v1 + 1024;
    float* coef_p2  = coef_v2 + 1024;

    // counting-sort scratch aliased into conv1o (dead until conv1 runs)
    uint2*    pairs = (uint2*)conv1o;                         // 2097152 x 8B = 4194304 f
    unsigned* cnt   = (unsigned*)(conv1o + 4194304);          // 262144
    unsigned* start = cnt + 262144;                           // 262160 (padded)
    unsigned* cur   = start + 262160;                         // 262144
    unsigned* bsum  = cur + 262144;                           // 256
    unsigned* boff  = bsum + 256;                             // 256

    size_t needed = (size_t)(coef_p2 + 1024 - ws) * sizeof(float);
    if (ws_size < needed) return;

    hipMemsetAsync(cnt, 0, (size_t)262144 * 4, stream);
    hipMemsetAsync(stats_p1, 0, (size_t)4096 * 4, stream);    // all 4 stats sets contiguous

    const size_t conv_lds = 104448 + 24576 + 512 + 512;       // 130048 B

    k_reorder_w<<<864, 256, 0, stream>>>(conv1_w, conv2_w, wrb);
    k_count<<<4096, 256, 0, stream>>>(points, features, cnt, stats_p1);
    k_coef<<<1, 512, 0, stream>>>(stats_p1, pg1g, pg1b, coef_p1);
    k_scan1<<<256, 256, 0, stream>>>(cnt, start, bsum);
    k_scan2<<<1, 256, 0, stream>>>(bsum, boff);
    k_scan3<<<256, 256, 0, stream>>>(start, boff, cur);
    k_fill<<<1024, 256, 0, stream>>>(points, cur, pairs);
    k_gather<<<2048, 256, 0, stream>>>(pairs, start, features, gridbuf, stats_v1);
    k_coef<<<1, 512, 0, stream>>>(stats_v1, g1_gamma, g1_beta, coef_v1);
    k_conv_mfma<<<1024, 512, conv_lds, stream>>>(gridbuf, wrb, conv1_b, coef_v1,
                                                 conv1o, stats_v2, nullptr, nullptr);
    k_coef<<<1, 512, 0, stream>>>(stats_v2, g2_gamma, g2_beta, coef_v2);
    k_conv_mfma<<<1024, 512, conv_lds, stream>>>(conv1o, wrb + 110592, conv2_b, coef_v2,
                                                 gridbuf, nullptr, gridbuf, coef_v1);
    k_point1<<<2048, 256, 0, stream>>>(features, p1w, p1b, coef_p1, h1b, stats_p2);
    k_coef<<<1, 512, 0, stream>>>(stats_p2, pg2g, pg2b, coef_p2);
    k_final<<<2048, 256, 0, stream>>>(points, features, h1b, p2w, p2b, coef_p1, coef_p2, gridbuf, out);
}

// Round 6
// 564.820 us; speedup vs baseline: 6.9377x; 1.0135x over previous
//
#include <hip/hip_runtime.h>

// Problem constants
#define BB 8
#define NB 32768
#define RR 32
#define VV (32*32*32)
#define TOTAL_PAIRS (BB*NB*8)          // 2097152
#define INV_SQRT2 0.70710678118654752440f

typedef __attribute__((ext_vector_type(8))) short s8v;      // 8 bf16 (MFMA A/B frag)
typedef __attribute__((ext_vector_type(8))) unsigned short u16x8;
typedef __attribute__((ext_vector_type(4))) float f4v;      // MFMA C/D frag

static __device__ __forceinline__ float lrelu(float x) { return x > 0.f ? x : 0.01f * x; }
static __device__ __forceinline__ unsigned short f2bf(float x) {
    unsigned u = __float_as_uint(x);
    u += 0x7fff + ((u >> 16) & 1);          // RNE
    return (unsigned short)(u >> 16);
}
static __device__ __forceinline__ float bf2f(unsigned short u) {
    return __uint_as_float(((unsigned)u) << 16);
}

static __device__ __forceinline__ void corner_setup(float px, float py, float pz,
    int& c0x, int& c0y, int& c0z, int& c1x, int& c1y, int& c1z,
    float& fx, float& fy, float& fz)
{
    float cx = fminf(fmaxf(px, 0.f), 1.f) * 31.f;
    float cy = fminf(fmaxf(py, 0.f), 1.f) * 31.f;
    float cz = fminf(fmaxf(pz, 0.f), 1.f) * 31.f;
    float f0x = floorf(cx), f0y = floorf(cy), f0z = floorf(cz);
    c0x = (int)f0x; c0y = (int)f0y; c0z = (int)f0z;
    fx = cx - f0x; fy = cy - f0y; fz = cz - f0z;
    c1x = min(c0x + 1, 31); c1y = min(c0y + 1, 31); c1z = min(c0z + 1, 31);
}

// Reorder conv weights [O][I][3][3][3] f32 -> bf16 [conv][tap9][col=o][k=dz*64+i],
// pre-XOR-swizzled within each 384B col-row.
__global__ __launch_bounds__(256) void k_reorder_w(const float* __restrict__ w1,
                                                   const float* __restrict__ w2,
                                                   unsigned short* __restrict__ wrb)
{
    int idx = blockIdx.x * 256 + threadIdx.x;
    if (idx >= 2 * 9 * 64 * 192) return;
    int conv = idx / 110592; int r = idx - conv * 110592;
    int tap = r / 12288; r -= tap * 12288;
    int col = r / 192; int k = r - col * 192;
    int dz = k >> 6, i = k & 63;
    int dx = tap / 3, dy = tap - dx * 3;
    const float* w = conv ? w2 : w1;
    float v = w[(col * 64 + i) * 27 + (dx * 9 + dy * 3 + dz)];
    int kd = k ^ ((col & 7) << 3);          // ushort-index form of byte ^ ((col&7)<<4)
    wrb[conv * 110592 + tap * 12288 + col * 192 + kd] = f2bf(v);
}

// Phase A: count (voxel,corner) pairs per voxel + point-branch GN1 stats.
__global__ __launch_bounds__(256) void k_count(const float* __restrict__ pts,
                                               const float* __restrict__ feat,
                                               unsigned* __restrict__ cnt,
                                               float* __restrict__ statsP)
{
    __shared__ float sred[256];
    const int b = blockIdx.x & 7;
    const int n0 = (blockIdx.x >> 3) * 64;
    const int wid = threadIdx.x >> 6, lane = threadIdx.x & 63;
    float s = 0.f, s2 = 0.f;
    for (int j = 0; j < 16; ++j) {
        const int base = b * NB + n0 + wid * 16 + j;
        const float f = feat[base * 64 + lane];
        s += f; s2 += f * f;
        const float px = pts[base * 3 + 0], py = pts[base * 3 + 1], pz = pts[base * 3 + 2];
        int c0x, c0y, c0z, c1x, c1y, c1z; float fx, fy, fz;
        corner_setup(px, py, pz, c0x, c0y, c0z, c1x, c1y, c1z, fx, fy, fz);
        if (lane < 8) {
            const int cx = (lane & 4) ? c1x : c0x;
            const int cy = (lane & 2) ? c1y : c0y;
            const int cz = (lane & 1) ? c1z : c0z;
            atomicAdd(&cnt[b * VV + (cx * RR + cy) * RR + cz], 1u);
        }
    }
    sred[threadIdx.x] = s; __syncthreads();
    if (threadIdx.x < 64) {
        float t = sred[threadIdx.x] + sred[threadIdx.x + 64] + sred[threadIdx.x + 128] + sred[threadIdx.x + 192];
        atomicAdd(&statsP[(b * 64 + threadIdx.x) * 2], t);
    }
    __syncthreads();
    sred[threadIdx.x] = s2; __syncthreads();
    if (threadIdx.x < 64) {
        float t = sred[threadIdx.x] + sred[threadIdx.x + 64] + sred[threadIdx.x + 128] + sred[threadIdx.x + 192];
        atomicAdd(&statsP[(b * 64 + threadIdx.x) * 2 + 1], t);
    }
}

// Scan step 1: per-block (1024 counts) exclusive scan; emit block totals.
__global__ __launch_bounds__(256) void k_scan1(const unsigned* __restrict__ cnt,
                                               unsigned* __restrict__ start,
                                               unsigned* __restrict__ bsum)
{
    __shared__ unsigned sd[256];
    const int t = threadIdx.x;
    const uint4 c = ((const uint4*)cnt)[blockIdx.x * 256 + t];
    unsigned tsum = c.x + c.y + c.z + c.w;
    sd[t] = tsum; __syncthreads();
    for (int off = 1; off < 256; off <<= 1) {
        unsigned x = (t >= off) ? sd[t - off] : 0u;
        __syncthreads();
        sd[t] += x;
        __syncthreads();
    }
    unsigned excl = (t == 0) ? 0u : sd[t - 1];
    uint4 o;
    o.x = excl; o.y = excl + c.x; o.z = o.y + c.y; o.w = o.z + c.z;
    ((uint4*)start)[blockIdx.x * 256 + t] = o;
    if (t == 255) bsum[blockIdx.x] = sd[255];
}

// Scan step 2: exclusive scan of 256 block sums.
__global__ void k_scan2(const unsigned* __restrict__ bsum, unsigned* __restrict__ boff)
{
    __shared__ unsigned sd[256];
    const int t = threadIdx.x;
    sd[t] = bsum[t]; __syncthreads();
    for (int off = 1; off < 256; off <<= 1) {
        unsigned x = (t >= off) ? sd[t - off] : 0u;
        __syncthreads();
        sd[t] += x;
        __syncthreads();
    }
    boff[t] = (t == 0) ? 0u : sd[t - 1];
}

// Scan step 3: add block offsets; also produce the working cursor copy.
__global__ __launch_bounds__(256) void k_scan3(unsigned* __restrict__ start,
                                               const unsigned* __restrict__ boff,
                                               unsigned* __restrict__ cur)
{
    const int g = blockIdx.x * 256 + threadIdx.x;
    const unsigned o = boff[blockIdx.x];
    uint4 v = ((uint4*)start)[g];
    v.x += o; v.y += o; v.z += o; v.w += o;
    ((uint4*)start)[g] = v;
    ((uint4*)cur)[g] = v;
}

// Phase C: write (point, weight) pairs into per-voxel segments. XCD-swizzled.
__global__ __launch_bounds__(256) void k_fill(const float* __restrict__ pts,
                                              unsigned* __restrict__ cur,
                                              uint2* __restrict__ pairs)
{
    const int b = blockIdx.x & 7;
    const int p = b * NB + (blockIdx.x >> 3) * 256 + threadIdx.x;
    const float px = pts[p * 3 + 0], py = pts[p * 3 + 1], pz = pts[p * 3 + 2];
    int c0x, c0y, c0z, c1x, c1y, c1z; float fx, fy, fz;
    corner_setup(px, py, pz, c0x, c0y, c0z, c1x, c1y, c1z, fx, fy, fz);
    const float w0x = 1.f - fx, w0y = 1.f - fy, w0z = 1.f - fz;
    const int bvv = b * VV;
#pragma unroll
    for (int k = 0; k < 8; ++k) {
        const int cx = (k & 4) ? c1x : c0x;
        const int cy = (k & 2) ? c1y : c0y;
        const int cz = (k & 1) ? c1z : c0z;
        const float w = ((k & 4) ? fx : w0x) * ((k & 2) ? fy : w0y) * ((k & 1) ? fz : w0z);
        unsigned slot = atomicAdd(&cur[bvv + (cx * RR + cy) * RR + cz], 1u);
        pairs[slot] = make_uint2((unsigned)p, __float_as_uint(w));
    }
}

// Phase D: per-voxel gather + normalize (bf16 grid out) + voxel GN1 stats. XCD-swizzled.
__global__ __launch_bounds__(256) void k_gather(const uint2* __restrict__ pairs,
                                                const unsigned* __restrict__ start,
                                                const float* __restrict__ feat,
                                                unsigned short* __restrict__ grid,
                                                float* __restrict__ statsV)
{
    __shared__ float sred[256];
    const int tid = threadIdx.x, wid = tid >> 6, lane = tid & 63;
    const int b = blockIdx.x & 7;
    const int vbase = b * VV + (blockIdx.x >> 3) * 128 + wid * 32;
    float s = 0.f, s2 = 0.f;
    for (int i = 0; i < 32; ++i) {
        const int v = vbase + i;
        const int p0 = start[v];
        const int p1 = (v == BB * VV - 1) ? TOTAL_PAIRS : (int)start[v + 1];
        float acc = 0.f, wsum = 0.f;
        for (int base = p0; base < p1; base += 64) {
            uint2 pr = make_uint2(0u, 0u);
            if (base + lane < p1) pr = pairs[base + lane];
            const int m = min(64, p1 - base);
            int j = 0;
            for (; j + 3 < m; j += 4) {
                unsigned u0 = (unsigned)__builtin_amdgcn_readlane((int)pr.x, j);
                unsigned u1 = (unsigned)__builtin_amdgcn_readlane((int)pr.x, j + 1);
                unsigned u2 = (unsigned)__builtin_amdgcn_readlane((int)pr.x, j + 2);
                unsigned u3 = (unsigned)__builtin_amdgcn_readlane((int)pr.x, j + 3);
                float w0 = __uint_as_float((unsigned)__builtin_amdgcn_readlane((int)pr.y, j));
                float w1 = __uint_as_float((unsigned)__builtin_amdgcn_readlane((int)pr.y, j + 1));
                float w2 = __uint_as_float((unsigned)__builtin_amdgcn_readlane((int)pr.y, j + 2));
                float w3 = __uint_as_float((unsigned)__builtin_amdgcn_readlane((int)pr.y, j + 3));
                float f0 = feat[(size_t)u0 * 64 + lane];
                float f1 = feat[(size_t)u1 * 64 + lane];
                float f2 = feat[(size_t)u2 * 64 + lane];
                float f3 = feat[(size_t)u3 * 64 + lane];
                acc = fmaf(w0, f0, acc); acc = fmaf(w1, f1, acc);
                acc = fmaf(w2, f2, acc); acc = fmaf(w3, f3, acc);
                wsum += w0 + w1 + w2 + w3;
            }
            for (; j < m; ++j) {
                unsigned u0 = (unsigned)__builtin_amdgcn_readlane((int)pr.x, j);
                float w0 = __uint_as_float((unsigned)__builtin_amdgcn_readlane((int)pr.y, j));
                acc = fmaf(w0, feat[(size_t)u0 * 64 + lane], acc);
                wsum += w0;
            }
        }
        const float val = acc / fmaxf(wsum, 1e-8f);
        grid[(size_t)v * 64 + lane] = f2bf(val);
        s += val; s2 += val * val;
    }
    sred[tid] = s; __syncthreads();
    if (tid < 64) {
        float t = sred[tid] + sred[tid + 64] + sred[tid + 128] + sred[tid + 192];
        atomicAdd(&statsV[(b * 64 + tid) * 2], t);
    }
    __syncthreads();
    sred[tid] = s2; __syncthreads();
    if (tid < 64) {
        float t = sred[tid] + sred[tid + 64] + sred[tid + 128] + sred[tid + 192];
        atomicAdd(&statsV[(b * 64 + tid) * 2 + 1], t);
    }
}

// stats -> per-channel affine (a,b): y = a*x + b implements groupnorm (groups of 2 ch x 32768).
__global__ void k_coef(const float* __restrict__ stats, const float* __restrict__ gamma,
                       const float* __restrict__ beta, float* __restrict__ coef)
{
    int tid = threadIdx.x;           // 512 threads: b=tid>>6, c=tid&63
    int b = tid >> 6, c = tid & 63, g = c >> 1;
    float s = stats[(b * 64 + 2 * g) * 2] + stats[(b * 64 + 2 * g + 1) * 2];
    float q = stats[(b * 64 + 2 * g) * 2 + 1] + stats[(b * 64 + 2 * g + 1) * 2 + 1];
    float mean = s / 65536.f;
    float var = q / 65536.f - mean * mean;
    float a = gamma[c] * rsqrtf(var + 1e-5f);
    coef[(b * 64 + c) * 2] = a;
    coef[(b * 64 + c) * 2 + 1] = beta[c] - mean * a;
}

// 3x3x3 conv C=64->64 SAME, bf16 implicit GEMM on MFMA. bf16 in/out grids.
// 256 thr / 4 waves; tile 2(x) x 4(y) x 16(z-half) = 128 voxels; wave owns 2 xy
// columns (M=16 each, a0/a1). LDS 80.9 KB -> 2 blocks/CU for cross-block overlap.
__global__ __launch_bounds__(256) void k_conv_mfma(const unsigned short* __restrict__ in,
                                                   const unsigned short* __restrict__ wrb,
                                                   const float* __restrict__ bias,
                                                   const float* __restrict__ coef_in,
                                                   unsigned short* out,
                                                   float* __restrict__ statsOut,
                                                   const unsigned short* resid,
                                                   const float* __restrict__ coef_res)
{
    extern __shared__ char smem[];
    unsigned short* in_lds = (unsigned short*)smem;                 // 432 rows x 128 B = 55296 B
    unsigned short* w_lds  = (unsigned short*)(smem + 55296);       // 12288 ushort = 24576 B
    float* ca    = (float*)(smem + 79872);                          // 64
    float* cb    = ca + 64;                                         // 64
    float* sstat = cb + 64;                                         // 128

    const int b = blockIdx.x & 7;
    const int t = blockIdx.x >> 3;            // 0..255
    const int zh = t & 1, ty = (t >> 1) & 7, tx = t >> 4;
    const int x0 = tx * 2, y0 = ty * 4, z0 = zh * 16;
    const int tid = threadIdx.x;

    if (tid < 64) {
        ca[tid] = coef_in[(b * 64 + tid) * 2];
        cb[tid] = coef_in[(b * 64 + tid) * 2 + 1];
    }
    if (tid < 128) sstat[tid] = 0.f;
    __syncthreads();

    // ---- stage input halo 4x6x18 (affine+lrelu fused), swizzled ds_write_b128 ----
    for (int g = tid; g < 3456; g += 256) {            // 432 rows x 8 granules
        int row = g >> 3, s = g & 7;
        int px = row / 108;                             // 6*18
        int rem = row - px * 108;
        int py = rem / 18;
        int pz = rem - py * 18;
        int gx = x0 + px - 1, gy = y0 + py - 1, gz = z0 + pz - 1;
        int byteoff = row * 128 + ((s * 16) ^ ((pz & 7) << 4));
        u16x8* dst = (u16x8*)((char*)in_lds + byteoff);
        u16x8 o;
        if ((unsigned)gx < 32u && (unsigned)gy < 32u && (unsigned)gz < 32u) {
            u16x8 v = *(const u16x8*)&in[((size_t)(b * VV + (gx * RR + gy) * RR + gz)) * 64 + s * 8];
            int ci = s * 8;
#pragma unroll
            for (int q = 0; q < 8; ++q)
                o[q] = f2bf(lrelu(fmaf(ca[ci + q], bf2f(v[q]), cb[ci + q])));
        } else {
            o = (u16x8)0;
        }
        *dst = o;
    }

    const int w = tid >> 6, l = tid & 63;
    const int l15 = l & 15, lq = l >> 4;
    const int col0 = 2 * w, col1 = 2 * w + 1;
    const int xi0 = col0 >> 2, yi0 = col0 & 3;
    const int xi1 = col1 >> 2, yi1 = col1 & 3;
    const int bxor = (l & 7) << 4;

    f4v acc[2][4];
#pragma unroll
    for (int nt = 0; nt < 4; ++nt) {
        float bv = bias[nt * 16 + l15];
        f4v bf = {bv, bv, bv, bv};
        acc[0][nt] = bf; acc[1][nt] = bf;
    }

    for (int tap = 0; tap < 9; ++tap) {
        __syncthreads();
        {   // stage this tap's weights: 96 B/thread linear copy (pre-swizzled global)
            const unsigned short* src = wrb + tap * 12288 + tid * 48;
            u16x8* d = (u16x8*)(w_lds + tid * 48);
#pragma unroll
            for (int q = 0; q < 6; ++q) d[q] = *(const u16x8*)(src + q * 8);
        }
        __syncthreads();
        const int dx = tap / 3, dy = tap - dx * 3;
        const int rb0 = ((xi0 + dx) * 6 + (yi0 + dy)) * 18;
        const int rb1 = ((xi1 + dx) * 6 + (yi1 + dy)) * 18;
#pragma unroll
        for (int ks = 0; ks < 6; ++ks) {
            const int dz = ks >> 1, cib = (ks & 1) * 32;
            const int pz = l15 + dz;
            const int chb = ((cib + lq * 8) * 2) ^ ((pz & 7) << 4);
            s8v a0 = *(const s8v*)((const char*)in_lds + (rb0 + pz) * 128 + chb);
            s8v a1 = *(const s8v*)((const char*)in_lds + (rb1 + pz) * 128 + chb);
#pragma unroll
            for (int nt = 0; nt < 4; ++nt) {
                int boff = (nt * 16 + l15) * 384 + ((ks * 64 + lq * 16) ^ bxor);
                s8v bf = *(const s8v*)((const char*)w_lds + boff);
                acc[0][nt] = __builtin_amdgcn_mfma_f32_16x16x32_bf16(a0, bf, acc[0][nt], 0, 0, 0);
                acc[1][nt] = __builtin_amdgcn_mfma_f32_16x16x32_bf16(a1, bf, acc[1][nt], 0, 0, 0);
            }
        }
    }

    // ---- epilogue (C frag: row z = lq*4+j, col ch = nt*16+l15) ----
    const size_t outb0 = ((size_t)(b * VV + ((x0 + xi0) * RR + (y0 + yi0)) * RR + z0)) * 64;
    const size_t outb1 = ((size_t)(b * VV + ((x0 + xi1) * RR + (y0 + yi1)) * RR + z0)) * 64;
    if (!resid) {
        // conv1: store bf16 + GN2 stats (f32 accs)
        float sa[4] = {0, 0, 0, 0}, sq[4] = {0, 0, 0, 0};
#pragma unroll
        for (int m = 0; m < 2; ++m) {
            const size_t ob = m ? outb1 : outb0;
#pragma unroll
            for (int nt = 0; nt < 4; ++nt)
#pragma unroll
                for (int j = 0; j < 4; ++j) {
                    int z = lq * 4 + j;
                    float v = acc[m][nt][j];
                    out[ob + (size_t)z * 64 + nt * 16 + l15] = f2bf(v);
                    sa[nt] += v; sq[nt] += v * v;
                }
        }
#pragma unroll
        for (int nt = 0; nt < 4; ++nt) {
            float a = sa[nt], q = sq[nt];
            a += __shfl_xor(a, 16); q += __shfl_xor(q, 16);
            a += __shfl_xor(a, 32); q += __shfl_xor(q, 32);
            if (lq == 0) {
                atomicAdd(&sstat[(nt * 16 + l15) * 2], a);
                atomicAdd(&sstat[(nt * 16 + l15) * 2 + 1], q);
            }
        }
        __syncthreads();
        if (tid < 128) atomicAdd(&statsOut[b * 128 + tid], sstat[tid]);
    } else {
        // conv2: out = (conv + affine(resid)) / sqrt2, bf16 in place over resid
#pragma unroll
        for (int nt = 0; nt < 4; ++nt) {
            int ch = nt * 16 + l15;
            float a2 = coef_res[(b * 64 + ch) * 2];
            float b2 = coef_res[(b * 64 + ch) * 2 + 1];
#pragma unroll
            for (int m = 0; m < 2; ++m) {
                const size_t ob = m ? outb1 : outb0;
#pragma unroll
                for (int j = 0; j < 4; ++j) {
                    int z = lq * 4 + j;
                    size_t idx = ob + (size_t)z * 64 + ch;
                    float r = bf2f(resid[idx]);
                    out[idx] = f2bf((acc[m][nt][j] + fmaf(a2, r, b2)) * INV_SQRT2);
                }
            }
        }
    }
}

// Point branch conv1x1 #1 on MFMA: h = W @ lrelu(gn1(f)) + bias; h stored bf16; GN2 stats.
__global__ __launch_bounds__(256) void k_point1(const float* __restrict__ feat,
                                                const float* __restrict__ W,
                                                const float* __restrict__ bias,
                                                const float* __restrict__ coefP,
                                                unsigned short* __restrict__ h1out,
                                                float* __restrict__ statsOut)
{
    __shared__ unsigned short actA[4][2048];   // [wave][32 pts][64 ch] swizzled
    __shared__ unsigned short wW[4096];        // [col=o][k=i] swizzled
    __shared__ float ca[64], cb[64];
    __shared__ float sstat[128];
    const int b = blockIdx.x & 7;
    const int n0 = (blockIdx.x >> 3) * 128;
    const int tid = threadIdx.x, w = tid >> 6, l = tid & 63;
    const int l15 = l & 15, lq = l >> 4;

    if (tid < 64) {
        ca[tid] = coefP[(b * 64 + tid) * 2];
        cb[tid] = coefP[(b * 64 + tid) * 2 + 1];
    }
    if (tid < 128) sstat[tid] = 0.f;
    {   // stage W (bf16, row-XOR swizzled)
        int o = tid >> 2, i0 = (tid & 3) * 16, sw = (o & 7) << 3;
        const float* src = W + o * 64 + i0;
#pragma unroll
        for (int q = 0; q < 16; ++q) wW[o * 64 + ((i0 + q) ^ sw)] = f2bf(src[q]);
    }
    __syncthreads();

    const int p = l >> 1, half = l & 1;
    const int gp = b * NB + n0 + w * 32 + p;
    {
        const float* src = feat + (size_t)gp * 64 + half * 32;
        const int sw = (p & 7) << 3;
#pragma unroll
        for (int q2 = 0; q2 < 4; ++q2) {
            float4 v0 = *(const float4*)(src + q2 * 8);
            float4 v1 = *(const float4*)(src + q2 * 8 + 4);
            float xs[8] = {v0.x, v0.y, v0.z, v0.w, v1.x, v1.y, v1.z, v1.w};
            int ci = half * 32 + q2 * 8;
            u16x8 o_;
#pragma unroll
            for (int q = 0; q < 8; ++q)
                o_[q] = f2bf(lrelu(fmaf(ca[ci + q], xs[q], cb[ci + q])));
            *(u16x8*)&actA[w][p * 64 + (ci ^ sw)] = o_;
        }
    }
    __syncthreads();

    f4v acc[2][4];
#pragma unroll
    for (int nt = 0; nt < 4; ++nt) {
        float bv = bias[nt * 16 + l15];
        f4v bf = {bv, bv, bv, bv};
        acc[0][nt] = bf; acc[1][nt] = bf;
    }
    const unsigned short* aw = actA[w];
#pragma unroll
    for (int kk = 0; kk < 2; ++kk) {
        s8v a0, a1;
        { int r = l15;      a0 = *(const s8v*)&aw[r * 64 + ((kk * 32 + lq * 8) ^ ((r & 7) << 3))]; }
        { int r = 16 + l15; a1 = *(const s8v*)&aw[r * 64 + ((kk * 32 + lq * 8) ^ ((r & 7) << 3))]; }
#pragma unroll
        for (int nt = 0; nt < 4; ++nt) {
            int col = nt * 16 + l15;
            s8v bf = *(const s8v*)&wW[col * 64 + ((kk * 32 + lq * 8) ^ ((col & 7) << 3))];
            acc[0][nt] = __builtin_amdgcn_mfma_f32_16x16x32_bf16(a0, bf, acc[0][nt], 0, 0, 0);
            acc[1][nt] = __builtin_amdgcn_mfma_f32_16x16x32_bf16(a1, bf, acc[1][nt], 0, 0, 0);
        }
    }

    float sa[4] = {0, 0, 0, 0}, sq[4] = {0, 0, 0, 0};
#pragma unroll
    for (int m = 0; m < 2; ++m)
#pragma unroll
        for (int nt = 0; nt < 4; ++nt)
#pragma unroll
            for (int j = 0; j < 4; ++j) {
                float v = acc[m][nt][j];
                sa[nt] += v; sq[nt] += v * v;
                actA[w][(m * 16 + lq * 4 + j) * 64 + nt * 16 + l15] = f2bf(v);
            }
#pragma unroll
    for (int nt = 0; nt < 4; ++nt) {
        float a = sa[nt], q = sq[nt];
        a += __shfl_xor(a, 16); q += __shfl_xor(q, 16);
        a += __shfl_xor(a, 32); q += __shfl_xor(q, 32);
        if (lq == 0) {
            atomicAdd(&sstat[(nt * 16 + l15) * 2], a);
            atomicAdd(&sstat[(nt * 16 + l15) * 2 + 1], q);
        }
    }
    {
        u16x8* dst = (u16x8*)(h1out + (size_t)gp * 64 + half * 32);
        const u16x8* srcl = (const u16x8*)&actA[w][p * 64 + half * 32];
        dst[0] = srcl[0]; dst[1] = srcl[1]; dst[2] = srcl[2]; dst[3] = srcl[3];
    }
    __syncthreads();
    if (tid < 128) atomicAdd(&statsOut[b * 128 + tid], sstat[tid]);
}

// Final fused on MFMA: point conv1x1 #2 (bf16 h1) + residual + devox gather (bf16 grid) + mix.
__global__ __launch_bounds__(256) void k_final(const float* __restrict__ pts,
                                               const float* __restrict__ feat,
                                               const unsigned short* __restrict__ h1,
                                               const float* __restrict__ W2,
                                               const float* __restrict__ bias2,
                                               const float* __restrict__ coefP1,
                                               const float* __restrict__ coefP2,
                                               const unsigned short* __restrict__ outg,
                                               float* __restrict__ out)
{
    __shared__ unsigned short actA[4][2048];
    __shared__ unsigned short wW[4096];
    __shared__ float ca1[64], cb1[64], ca2[64], cb2[64];
    __shared__ float po[128 * 65];
    const int b = blockIdx.x & 7;
    const int n0 = (blockIdx.x >> 3) * 128;
    const int tid = threadIdx.x, w = tid >> 6, l = tid & 63;
    const int l15 = l & 15, lq = l >> 4;

    if (tid < 64) {
        ca1[tid] = coefP1[(b * 64 + tid) * 2];
        cb1[tid] = coefP1[(b * 64 + tid) * 2 + 1];
        ca2[tid] = coefP2[(b * 64 + tid) * 2];
        cb2[tid] = coefP2[(b * 64 + tid) * 2 + 1];
    }
    {
        int o = tid >> 2, i0 = (tid & 3) * 16, sw = (o & 7) << 3;
        const float* src = W2 + o * 64 + i0;
#pragma unroll
        for (int q = 0; q < 16; ++q) wW[o * 64 + ((i0 + q) ^ sw)] = f2bf(src[q]);
    }
    __syncthreads();

    const int p = l >> 1, half = l & 1;
    const int gp = b * NB + n0 + w * 32 + p;
    {
        const u16x8* src = (const u16x8*)(h1 + (size_t)gp * 64 + half * 32);
        const int sw = (p & 7) << 3;
#pragma unroll
        for (int q2 = 0; q2 < 4; ++q2) {
            u16x8 hv = src[q2];
            int ci = half * 32 + q2 * 8;
            u16x8 o_;
#pragma unroll
            for (int q = 0; q < 8; ++q)
                o_[q] = f2bf(lrelu(fmaf(ca2[ci + q], bf2f(hv[q]), cb2[ci + q])));
            *(u16x8*)&actA[w][p * 64 + (ci ^ sw)] = o_;
        }
    }
    __syncthreads();

    f4v acc[2][4];
#pragma unroll
    for (int nt = 0; nt < 4; ++nt) {
        float bv = bias2[nt * 16 + l15];
        f4v bf = {bv, bv, bv, bv};
        acc[0][nt] = bf; acc[1][nt] = bf;
    }
    const unsigned short* aw = actA[w];
#pragma unroll
    for (int kk = 0; kk < 2; ++kk) {
        s8v a0, a1;
        { int r = l15;      a0 = *(const s8v*)&aw[r * 64 + ((kk * 32 + lq * 8) ^ ((r & 7) << 3))]; }
        { int r = 16 + l15; a1 = *(const s8v*)&aw[r * 64 + ((kk * 32 + lq * 8) ^ ((r & 7) << 3))]; }
#pragma unroll
        for (int nt = 0; nt < 4; ++nt) {
            int col = nt * 16 + l15;
            s8v bf = *(const s8v*)&wW[col * 64 + ((kk * 32 + lq * 8) ^ ((col & 7) << 3))];
            acc[0][nt] = __builtin_amdgcn_mfma_f32_16x16x32_bf16(a0, bf, acc[0][nt], 0, 0, 0);
            acc[1][nt] = __builtin_amdgcn_mfma_f32_16x16x32_bf16(a1, bf, acc[1][nt], 0, 0, 0);
        }
    }
#pragma unroll
    for (int m = 0; m < 2; ++m)
#pragma unroll
        for (int nt = 0; nt < 4; ++nt)
#pragma unroll
            for (int j = 0; j < 4; ++j)
                po[(w * 32 + m * 16 + lq * 4 + j) * 65 + nt * 16 + l15] = acc[m][nt][j];
    __syncthreads();

    // Phase 2: per-point devox (bf16 grid) + residual + mix (lane = channel)
    for (int i = 0; i < 32; ++i) {
        const int pl = w * 32 + i;
        const int g2 = b * NB + n0 + pl;
        const float f = feat[(size_t)g2 * 64 + l];
        const float fn = fmaf(ca1[l], f, cb1[l]);
        const float o = po[pl * 65 + l];
        const float ptsv = (o + fn) * INV_SQRT2;
        const float px = pts[g2 * 3 + 0], py = pts[g2 * 3 + 1], pz = pts[g2 * 3 + 2];
        int c0x, c0y, c0z, c1x, c1y, c1z; float fx, fy, fz;
        corner_setup(px, py, pz, c0x, c0y, c0z, c1x, c1y, c1z, fx, fy, fz);
        const float w0x = 1.f - fx, w0y = 1.f - fy, w0z = 1.f - fz;
        float dv = 0.f;
#pragma unroll
        for (int k = 0; k < 8; ++k) {
            const int cx = (k & 4) ? c1x : c0x;
            const int cy = (k & 2) ? c1y : c0y;
            const int cz = (k & 1) ? c1z : c0z;
            const float wgt = ((k & 4) ? fx : w0x) * ((k & 2) ? fy : w0y) * ((k & 1) ? fz : w0z);
            dv = fmaf(wgt, bf2f(outg[((size_t)(b * VV + (cx * RR + cy) * RR + cz)) * 64 + l]), dv);
        }
        out[(size_t)g2 * 64 + l] = (ptsv + dv) * INV_SQRT2;
    }
}

extern "C" void kernel_launch(void* const* d_in, const int* in_sizes, int n_in,
                              void* d_out, int out_size, void* d_ws, size_t ws_size,
                              hipStream_t stream)
{
    const float* points   = (const float*)d_in[0];
    const float* features = (const float*)d_in[1];
    const float* conv1_w  = (const float*)d_in[2];
    const float* conv1_b  = (const float*)d_in[3];
    const float* conv2_w  = (const float*)d_in[4];
    const float* conv2_b  = (const float*)d_in[5];
    const float* g1_gamma = (const float*)d_in[6];
    const float* g1_beta  = (const float*)d_in[7];
    const float* g2_gamma = (const float*)d_in[8];
    const float* g2_beta  = (const float*)d_in[9];
    const float* p1w  = (const float*)d_in[10];
    const float* p1b  = (const float*)d_in[11];
    const float* p2w  = (const float*)d_in[12];
    const float* p2b  = (const float*)d_in[13];
    const float* pg1g = (const float*)d_in[14];
    const float* pg1b = (const float*)d_in[15];
    const float* pg2g = (const float*)d_in[16];
    const float* pg2b = (const float*)d_in[17];
    float* out = (float*)d_out;

    // All grid/h1 buffers bf16 now.
    unsigned short* gridbuf = (unsigned short*)d_ws;          // 16777216 u16: grid -> out_grid (in place)
    unsigned short* conv1o  = gridbuf + 16777216;             // 16777216 u16 (sort scratch aliased inside)
    unsigned short* h1b     = conv1o + 16777216;              // 16777216 u16
    unsigned short* wrb     = h1b + 16777216;                 // 221184 u16
    float* stats_p1 = (float*)(wrb + 221184);                 // 1024 f each
    float* stats_v1 = stats_p1 + 1024;
    float* stats_v2 = stats_v1 + 1024;
    float* stats_p2 = stats_v2 + 1024;
    float* coef_p1  = stats_p2 + 1024;
    float* coef_v1  = coef_p1 + 1024;
    float* coef_v2  = coef_v1 + 1024;
    float* coef_p2  = coef_v2 + 1024;

    // counting-sort scratch aliased into conv1o region (dead until conv1 runs)
    uint2*    pairs = (uint2*)conv1o;                         // 16777216 B
    unsigned* cnt   = (unsigned*)(conv1o + 8388608);          // 262144 u32
    unsigned* start = cnt + 262144;                           // 262160 (padded)
    unsigned* cur   = start + 262160;                         // 262144
    unsigned* bsum  = cur + 262144;                           // 256
    unsigned* boff  = bsum + 256;                             // 256

    size_t needed = (size_t)((char*)(coef_p2 + 1024) - (char*)d_ws);
    if (ws_size < needed) return;

    hipMemsetAsync(cnt, 0, (size_t)262144 * 4, stream);
    hipMemsetAsync(stats_p1, 0, (size_t)4096 * 4, stream);    // all 4 stats sets contiguous

    const size_t conv_lds = 55296 + 24576 + 256 + 256 + 512;  // 80896 B -> 2 blocks/CU

    k_reorder_w<<<864, 256, 0, stream>>>(conv1_w, conv2_w, wrb);
    k_count<<<4096, 256, 0, stream>>>(points, features, cnt, stats_p1);
    k_coef<<<1, 512, 0, stream>>>(stats_p1, pg1g, pg1b, coef_p1);
    k_scan1<<<256, 256, 0, stream>>>(cnt, start, bsum);
    k_scan2<<<1, 256, 0, stream>>>(bsum, boff);
    k_scan3<<<256, 256, 0, stream>>>(start, boff, cur);
    k_fill<<<1024, 256, 0, stream>>>(points, cur, pairs);
    k_gather<<<2048, 256, 0, stream>>>(pairs, start, features, gridbuf, stats_v1);
    k_coef<<<1, 512, 0, stream>>>(stats_v1, g1_gamma, g1_beta, coef_v1);
    k_conv_mfma<<<2048, 256, conv_lds, stream>>>(gridbuf, wrb, conv1_b, coef_v1,
                                                 conv1o, stats_v2, nullptr, nullptr);
    k_coef<<<1, 512, 0, stream>>>(stats_v2, g2_gamma, g2_beta, coef_v2);
    k_conv_mfma<<<2048, 256, conv_lds, stream>>>(conv1o, wrb + 110592, conv2_b, coef_v2,
                                                 gridbuf, nullptr, gridbuf, coef_v1);
    k_point1<<<2048, 256, 0, stream>>>(features, p1w, p1b, coef_p1, h1b, stats_p2);
    k_coef<<<1, 512, 0, stream>>>(stats_p2, pg2g, pg2b, coef_p2);
    k_final<<<2048, 256, 0, stream>>>(points, features, h1b, p2w, p2b, coef_p1, coef_p2, gridbuf, out);
}